// Round 4
// baseline (36657.825 us; speedup 1.0000x reference)
//
#include <hip/hip_runtime.h>
#include <hip/hip_bf16.h>
#include <cstdint>

#define NB 64      // batch
#define SL 1024    // seq len
#define ED 128     // embed
#define HD 256     // hidden
#define NT 35      // tags
#define TSTART 33

typedef unsigned int uint;
typedef __attribute__((ext_vector_type(8))) short short8;
typedef __attribute__((ext_vector_type(4))) float floatx4;
typedef __attribute__((ext_vector_type(4))) uint uintx4;

#define EXHALF 16384   // dwords per slot: 2dir*4bg*16b*128dw

__device__ __forceinline__ float fsig(float x){
  return __builtin_amdgcn_rcpf(1.f + __expf(-x));
}
__device__ __forceinline__ float ftanh(float x){
  float ax = fabsf(x);
  float e  = __expf(2.f*ax);
  float r  = 1.f - 2.f*__builtin_amdgcn_rcpf(e+1.f);
  return copysignf(r, x);
}
__device__ __forceinline__ unsigned short f2bf(float f){
  __hip_bfloat16 b = __float2bfloat16(f);
  return __builtin_bit_cast(unsigned short, b);
}
__device__ __forceinline__ uint pk2(float a, float b){
  return (uint)f2bf(a) | ((uint)f2bf(b)<<16);
}

// K-1: init exchange buffers to bit0=1 (tag mismatch; rejects 0xAA poison too),
// xcdtab to 0. Re-run every launch for determinism.
__global__ void zero_kernel(uint* __restrict__ exchS, uint* __restrict__ exchF,
                            uint* __restrict__ xcdtab){
  int i = blockIdx.x*blockDim.x + threadIdx.x;
  if (i < 2*EXHALF){ exchS[i] = 1u; exchF[i] = 1u; }
  if (i < 64) xcdtab[i] = 0u;
}

// K0: pre-gather x = bf16(emb[data]) : [B][L][128] bf16 (16 uint4 per row)
__global__ void xgather_kernel(const int* __restrict__ data, const float* __restrict__ emb,
                               uint4* __restrict__ xbf){
  int i = blockIdx.x*blockDim.x + threadIdx.x;   // NB*SL*16
  if (i >= NB*SL*16) return;
  int bt = i >> 4;
  int c  = i & 15;
  int token = data[bt];
  const float4* ep = (const float4*)(emb + (size_t)token*ED + c*8);
  float4 e0 = ep[0], e1 = ep[1];
  uint4 xv;
  xv.x = pk2(e0.x, e0.y); xv.y = pk2(e0.z, e0.w);
  xv.z = pk2(e1.x, e1.y); xv.w = pk2(e1.z, e1.w);
  xbf[(size_t)bt*16 + c] = xv;
}

// K1: persistent clustered BiLSTM, parity-tagged lock-free h exchange.
// Block remap: kblk = blockIdx>>3, cl = blockIdx&7 -> cluster members share
// blockIdx%8 (same XCD under round-robin dispatch). Exchange protocol:
//  - producers dual-store each tagged h dword: plain store -> exchF (local-XCD
//    L2 path) AND agent atomic -> exchS (MALL path).
//  - consumers check the publisher XCD table: same-XCD -> poll exchF with sc0
//    (L1-bypass, L2-hit) dwordx4 loads, bounded 256 tries, then fall back to
//    the unbounded agent-scope exchS poll. Correct under ANY XCD mapping.
__global__ __launch_bounds__(256, 1) void lstm_cluster(
    const uint4* __restrict__ xbf,
    const float* __restrict__ wihf, const float* __restrict__ whhf,
    const float* __restrict__ bihf, const float* __restrict__ bhhf,
    const float* __restrict__ wihb, const float* __restrict__ whhb,
    const float* __restrict__ bihb, const float* __restrict__ bhhb,
    uint* __restrict__ exchS, uint* __restrict__ exchF, uint* __restrict__ xcdtab,
    uint* __restrict__ hf, uint* __restrict__ hb){
  const int tid  = threadIdx.x;
  const int lane = tid & 63;
  const int w    = tid >> 6;            // wave id == gate id (i,f,g,o)
  const int kblk = blockIdx.x >> 3;     // unit slice [32*kblk, 32*kblk+32)
  const int cl   = blockIdx.x & 7;      // cluster id == dir*4+bg
  const int dir  = cl >> 2;
  const int bg   = cl & 3;

  __shared__ __align__(16) unsigned short xh[16*384]; // [b][k] bf16, XOR-swizzled
  __shared__ float gsm[128*17];                       // [row][batch] padded

  const float* Wih = dir ? wihb : wihf;
  const float* Whh = dir ? whhb : whhf;
  const float* Bih = dir ? bihb : bihf;
  const float* Bhh = dir ? bhhb : bhhf;

  // ---- publish my XCD id; discover peer XCDs ----
  uint myxcc;
  asm volatile("s_getreg_b32 %0, hwreg(HW_REG_XCC_ID)" : "=s"(myxcc));
  myxcc &= 0xFu;
  if (tid == 0)
    __hip_atomic_store(&xcdtab[blockIdx.x], myxcc | 0x100u,
                       __ATOMIC_RELAXED, __HIP_MEMORY_SCOPE_AGENT);

  // ---- one-time: weight B-fragments into registers ----
  short8 bfrag[2][12];
  float bias2[2];
  const int koff = (lane>>4)*8;
  #pragma unroll
  for (int tau=0; tau<2; ++tau){
    int ul = tau*16 + (lane&15);
    int R  = w*256 + kblk*32 + ul;
    bias2[tau] = Bih[R] + Bhh[R];
    #pragma unroll
    for (int s=0; s<12; ++s){
      const float* src = (s<4) ? (Wih + (size_t)R*ED + s*32 + koff)
                               : (Whh + (size_t)R*HD + (s-4)*32 + koff);
      float4 f0 = ((const float4*)src)[0];
      float4 f1 = ((const float4*)src)[1];
      short8 v;
      v[0]=(short)f2bf(f0.x); v[1]=(short)f2bf(f0.y);
      v[2]=(short)f2bf(f0.z); v[3]=(short)f2bf(f0.w);
      v[4]=(short)f2bf(f1.x); v[5]=(short)f2bf(f1.y);
      v[6]=(short)f2bf(f1.z); v[7]=(short)f2bf(f1.w);
      bfrag[tau][s] = v;
    }
  }

  const int sb = tid >> 4;          // staging batch
  const int sc = tid & 15;          // staging chunk
  const int ub = tid >> 4;          // update batch
  const int up = tid & 15;          // update unit-pair
  const int arow  = lane & 15;
  const int abase = arow*768 + (lane>>4)*16;
  const int aswz  = (arow & 7) << 4;
  char* xhb = (char*)xh;

  // my staging reads come from cluster member ms = sc>>1 (blockIdx ms*8+cl)
  const int ms = sc >> 1;
  uint peer;
  do {
    peer = __hip_atomic_load(&xcdtab[ms*8+cl], __ATOMIC_RELAXED, __HIP_MEMORY_SCOPE_AGENT);
  } while (!(peer & 0x100u));
  const bool fastp = ((peer & 0xFu) == myxcc);

  uint* hout = dir ? hb : hf;
  const size_t exrd_base = (size_t)(cl*16 + sb)*128 + sc*8;
  const size_t exwr_base = (size_t)(cl*16 + ub)*128 + kblk*16 + up;
  const size_t xrow_base = (size_t)(bg*16+sb)*SL;

  float creg0 = 0.f, creg1 = 0.f;

  for (int t=0; t<SL; ++t){
    const int tt = dir ? (SL-1-t) : t;

    // ---- issue x load (independent of h) ----
    uint4 xv = xbf[(xrow_base + tt)*16 + sc];

    // ---- h(t-1): poll parity-tagged exchange ----
    uintx4 h0v, h1v;
    if (t == 0){
      h0v = 0; h1v = 0;
    } else {
      const uint slot = (uint)(t-1)&1u;
      const uint expect = ((uint)(t-1)>>1)&1u;
      bool got = false;
      if (fastp){
        const uint* exr = exchF + (size_t)slot*EXHALF + exrd_base;
        int tries = 256;
        for (;;){
          uintx4 A, B;
          asm volatile("global_load_dwordx4 %0, %2, off sc0\n\t"
                       "global_load_dwordx4 %1, %3, off sc0\n\t"
                       "s_waitcnt vmcnt(0)"
                       : "=v"(A), "=v"(B) : "v"(exr), "v"(exr+4));
          uint bad = ((A[0]^expect)|(A[1]^expect)|(A[2]^expect)|(A[3]^expect)
                     |(B[0]^expect)|(B[1]^expect)|(B[2]^expect)|(B[3]^expect)) & 1u;
          if (!bad){ h0v = A & ~1u; h1v = B & ~1u; got = true; break; }
          if (--tries == 0) break;   // fall back to safe path
        }
      }
      if (!got){
        const uint* exr = exchS + (size_t)slot*EXHALF + exrd_base;
        uint hv[8];
        for (;;){
          uint ok = 1u;
          #pragma unroll
          for (int j=0;j<8;++j)
            hv[j] = __hip_atomic_load(exr+j, __ATOMIC_RELAXED, __HIP_MEMORY_SCOPE_AGENT);
          #pragma unroll
          for (int j=0;j<8;++j) ok &= (uint)((hv[j]&1u)==expect);
          if (ok) break;
        }
        h0v[0]=hv[0]&~1u; h0v[1]=hv[1]&~1u; h0v[2]=hv[2]&~1u; h0v[3]=hv[3]&~1u;
        h1v[0]=hv[4]&~1u; h1v[1]=hv[5]&~1u; h1v[2]=hv[6]&~1u; h1v[3]=hv[7]&~1u;
      }
    }

    // ---- stage x + h into swizzled LDS ----
    *(uint4*)(xhb + ((sb*768 + sc*16) ^ ((sb&7)<<4))) = xv;
    *(uintx4*)(xhb + ((sb*768 + 256 + sc*32)      ^ ((sb&7)<<4))) = h0v;
    *(uintx4*)(xhb + ((sb*768 + 256 + sc*32 + 16) ^ ((sb&7)<<4))) = h1v;
    __syncthreads();   // staging done; also orders update(t-1) gsm reads vs writes below

    // ---- MFMA: gates[16 batch][32 rows of this wave] ----
    floatx4 acc0; acc0[0]=bias2[0]; acc0[1]=bias2[0]; acc0[2]=bias2[0]; acc0[3]=bias2[0];
    floatx4 acc1; acc1[0]=bias2[1]; acc1[1]=bias2[1]; acc1[2]=bias2[1]; acc1[3]=bias2[1];
    #pragma unroll
    for (int s=0; s<12; ++s){
      short8 afrag = *(const short8*)(xhb + ((abase + s*64) ^ aswz));
      acc0 = __builtin_amdgcn_mfma_f32_16x16x32_bf16(afrag, bfrag[0][s], acc0, 0,0,0);
      acc1 = __builtin_amdgcn_mfma_f32_16x16x32_bf16(afrag, bfrag[1][s], acc1, 0,0,0);
    }
    {
      int gn = w*32 + (lane&15);
      int gm = (lane>>4)*4;
      #pragma unroll
      for (int j=0;j<4;++j){
        gsm[(gn   )*17 + gm + j] = acc0[j];
        gsm[(gn+16)*17 + gm + j] = acc1[j];
      }
    }
    __syncthreads();   // gsm ready; also orders MFMA xh reads vs next staging writes

    // ---- c/h update for units (2up, 2up+1), batch ub ----
    {
      int u0 = 2*up, u1 = 2*up+1;
      float gi0 = gsm[(0*32+u0)*17+ub], gf0 = gsm[(1*32+u0)*17+ub];
      float gg0 = gsm[(2*32+u0)*17+ub], go0 = gsm[(3*32+u0)*17+ub];
      float gi1 = gsm[(0*32+u1)*17+ub], gf1 = gsm[(1*32+u1)*17+ub];
      float gg1 = gsm[(2*32+u1)*17+ub], go1 = gsm[(3*32+u1)*17+ub];
      float c0 = fsig(gf0)*creg0 + fsig(gi0)*ftanh(gg0); creg0 = c0;
      float c1 = fsig(gf1)*creg1 + fsig(gi1)*ftanh(gg1); creg1 = c1;
      float h0f = fsig(go0)*ftanh(c0);
      float h1f = fsig(go1)*ftanh(c1);
      uint hpack = pk2(h0f, h1f);
      uint exv = (hpack & ~1u) | ((uint)(t>>1)&1u);   // parity tag in bit0
      uint* exwF = exchF + (size_t)(t&1)*EXHALF + exwr_base;
      uint* exwS = exchS + (size_t)(t&1)*EXHALF + exwr_base;
      asm volatile("global_store_dword %0, %1, off" :: "v"(exwF), "v"(exv) : "memory");
      __hip_atomic_store(exwS, exv, __ATOMIC_RELAXED, __HIP_MEMORY_SCOPE_AGENT);
      hout[(xrow_base + tt)*128 + kblk*16 + up] = hpack;
    }
    // no end barrier: next sync1 orders gsm reads vs next gsm writes.
  }
}

// K2: emission GEMM via MFMA: [65536 rows x 512] @ [512 x 48(35)] -> emis fp32.
// 512 blocks x 256 thr (4 waves). Block: 128 rows; cls_w bf16 staged in LDS.
__global__ __launch_bounds__(256) void emis_mfma(
    const unsigned short* __restrict__ hfu, const unsigned short* __restrict__ hbu,
    const float* __restrict__ clsw, const float* __restrict__ clsb,
    float* __restrict__ emis){
  __shared__ unsigned short wsm[48*520];              // bf16 [48][520], 512 used
  __shared__ __align__(16) unsigned short alds[128*40]; // [128][40] u16 (80B pitch)
  const int tid = threadIdx.x;
  const int lane = tid & 63;
  const int wid  = tid >> 6;
  // stage cls_w -> bf16 LDS (rows 35..47 zero), 4 elems per iter
  for (int i=tid; i<6144; i+=256){
    int r = i >> 7, c4 = (i & 127)*4;
    uint2 pv;
    if (r < 35){
      float4 v = *(const float4*)(clsw + (size_t)r*512 + c4);
      pv.x = pk2(v.x, v.y); pv.y = pk2(v.z, v.w);
    } else { pv.x = 0u; pv.y = 0u; }
    *(uint2*)(wsm + r*520 + c4) = pv;
  }
  __syncthreads();
  floatx4 acc[2][3];
  #pragma unroll
  for (int mt=0;mt<2;++mt)
    #pragma unroll
    for (int nt=0;nt<3;++nt){ acc[mt][nt][0]=0;acc[mt][nt][1]=0;acc[mt][nt][2]=0;acc[mt][nt][3]=0; }

  const size_t row0 = (size_t)blockIdx.x*128;
  for (int ks=0; ks<16; ++ks){
    const unsigned short* hsrc = (ks<8) ? hfu : hbu;
    const int col = (ks&7)*32;
    __syncthreads();   // previous ks's alds reads done
    #pragma unroll
    for (int q=0;q<2;++q){
      int j = tid*2+q;           // 0..511
      int r = j>>2, c4 = j&3;
      uint4 v = *(const uint4*)(hsrc + (row0 + r)*256 + col + c4*8);
      *(uint4*)((char*)alds + r*80 + c4*16) = v;
    }
    __syncthreads();
    short8 bf[3];
    #pragma unroll
    for (int nt=0;nt<3;++nt){
      int rr = nt*16 + (lane&15);
      bf[nt] = *(const short8*)(wsm + rr*520 + ks*32 + (lane>>4)*8);
    }
    #pragma unroll
    for (int mt=0;mt<2;++mt){
      int r = (wid*2+mt)*16 + (lane&15);
      short8 af = *(const short8*)((char*)alds + r*80 + (lane>>4)*16);
      #pragma unroll
      for (int nt=0;nt<3;++nt)
        acc[mt][nt] = __builtin_amdgcn_mfma_f32_16x16x32_bf16(af, bf[nt], acc[mt][nt], 0,0,0);
    }
  }
  // epilogue: D[m][n]: n=lane&15 (tag), m=(lane>>4)*4+j
  #pragma unroll
  for (int mt=0;mt<2;++mt){
    #pragma unroll
    for (int nt=0;nt<3;++nt){
      int tag = nt*16 + (lane&15);
      if (tag < NT){
        float bv = clsb[tag];
        #pragma unroll
        for (int j=0;j<4;++j){
          int m = (wid*2+mt)*16 + (lane>>4)*4 + j;
          emis[(row0 + m)*NT + tag] = acc[mt][nt][j] + bv;
        }
      }
    }
  }
}

// K3: gold score + CRF forward. 1 wave per batch, wave-synchronous (no barriers),
// E rows in registers, aL in LDS (broadcast reads), 4-way dot chains.
__global__ void crf_kernel(const float* __restrict__ emis, const float* __restrict__ trans,
                           const int* __restrict__ tags, float* __restrict__ diff){
  const int b = blockIdx.x, l = threadIdx.x;   // 64 threads = 1 wave
  __shared__ float aLds[64];
  // gold score (all 64 lanes)
  float gp = 0.f;
  for (int t=l; t<SL; t+=64){
    int tg = tags[b*SL+t];
    int pv = (t>0) ? tags[b*SL+t-1] : TSTART;
    gp += emis[((size_t)(b*SL)+t)*NT + tg] + trans[tg*NT+pv];
  }
  #pragma unroll
  for (int m=1;m<64;m<<=1) gp += __shfl_xor(gp, m);
  // E row for my tag in registers (lanes >= NT hold zeros)
  float Erow[NT];
  #pragma unroll
  for (int p=0;p<NT;++p) Erow[p] = (l<NT) ? __expf(trans[l*NT+p]) : 0.f;
  aLds[l] = (l==TSTART) ? 1.f : 0.f;
  float logZ = 0.f;
  const float* ep = emis + (size_t)b*SL*NT;
  float epre = (l<NT) ? ep[l] : 0.f;
  for (int t=0; t<SL; ++t){
    float ev = __expf(epre);
    int tn = (t+1 < SL) ? (t+1) : (SL-1);
    epre = (l<NT) ? ep[(size_t)tn*NT + l] : 0.f;
    float s0=0.f, s1=0.f, s2=0.f, s3=0.f;
    #pragma unroll
    for (int p=0;p<32;p+=4){
      s0 += Erow[p  ]*aLds[p  ];
      s1 += Erow[p+1]*aLds[p+1];
      s2 += Erow[p+2]*aLds[p+2];
      s3 += Erow[p+3]*aLds[p+3];
    }
    s0 += Erow[32]*aLds[32];
    s1 += Erow[33]*aLds[33];
    s2 += Erow[34]*aLds[34];
    float v = ((s0+s1)+(s2+s3)) * ev;      // lanes >= NT: 0
    float tot = v;
    #pragma unroll
    for (int m=1;m<64;m<<=1) tot += __shfl_xor(tot, m);
    logZ += __logf(tot);
    aLds[l] = v * __builtin_amdgcn_rcpf(tot);   // wave-order LDS: next reads see this
  }
  if (l == 0) diff[b] = logZ - gp;
}

// K4: loss = mean(diff)
__global__ void final_kernel(const float* __restrict__ diff, float* __restrict__ out){
  int l = threadIdx.x;
  float v = diff[l];
  #pragma unroll
  for (int m=1;m<64;m<<=1) v += __shfl_xor(v, m);
  if (l == 0) out[0] = v * (1.f/64.f);
}

extern "C" void kernel_launch(void* const* d_in, const int* in_sizes, int n_in,
                              void* d_out, int out_size, void* d_ws, size_t ws_size,
                              hipStream_t stream){
  const int*   data = (const int*)d_in[0];
  const int*   tags = (const int*)d_in[2];
  const float* emb  = (const float*)d_in[3];
  const float* wihf = (const float*)d_in[4];
  const float* whhf = (const float*)d_in[5];
  const float* bihf = (const float*)d_in[6];
  const float* bhhf = (const float*)d_in[7];
  const float* wihb = (const float*)d_in[8];
  const float* whhb = (const float*)d_in[9];
  const float* bihb = (const float*)d_in[10];
  const float* bhhb = (const float*)d_in[11];
  const float* clsw = (const float*)d_in[12];
  const float* clsb = (const float*)d_in[13];
  const float* trans= (const float*)d_in[14];

  char* ws = (char*)d_ws;
  uint*  hf    = (uint*)(ws);                    // 33,554,432 B (bf16 [B][L][256])
  uint*  hb    = (uint*)(ws + 33554432);         // 33,554,432 B
  uint4* xbf   = (uint4*)(ws + 67108864);        // 16,777,216 B (bf16 x, lstm-only)
  float* emis  = (float*)(ws + 67108864);        //  9,175,040 B (overlays xbf post-lstm)
  uint*  exchS = (uint*)(ws + 83886080);         //    131,072 B (MALL path)
  uint*  exchF = (uint*)(ws + 84017152);         //    131,072 B (L2 path)
  uint*  xcdtab= (uint*)(ws + 84148224);         //        256 B
  float* diff  = (float*)(ws + 84148480);        //        256 B
  float* out   = (float*)d_out;

  zero_kernel<<<dim3(128), dim3(256), 0, stream>>>(exchS, exchF, xcdtab);
  xgather_kernel<<<dim3(4096), dim3(256), 0, stream>>>(data, emb, xbf);
  lstm_cluster<<<dim3(64), dim3(256), 0, stream>>>(
      xbf, wihf, whhf, bihf, bhhf, wihb, whhb, bihb, bhhb,
      exchS, exchF, xcdtab, hf, hb);
  emis_mfma<<<dim3(512), dim3(256), 0, stream>>>(
      (const unsigned short*)hf, (const unsigned short*)hb, clsw, clsb, emis);
  crf_kernel<<<dim3(64), dim3(64), 0, stream>>>(emis, trans, tags, diff);
  final_kernel<<<dim3(1), dim3(64), 0, stream>>>(diff, out);
}

// Round 5
// 10533.756 us; speedup vs baseline: 3.4800x; 3.4800x over previous
//
#include <hip/hip_runtime.h>
#include <hip/hip_bf16.h>
#include <cstdint>

#define NB 64      // batch
#define SL 1024    // seq len
#define ED 128     // embed
#define HD 256     // hidden
#define NT 35      // tags
#define TSTART 33

typedef unsigned int uint;
typedef __attribute__((ext_vector_type(8))) short short8;
typedef __attribute__((ext_vector_type(4))) float floatx4;
typedef __attribute__((ext_vector_type(4))) uint uintx4;

#define EXHALF 16384   // dwords per slot: 2dir*4bg*16b*128dw
#define NG 4           // batch-groups (chains) interleaved per block

__device__ __forceinline__ float fsig(float x){
  return __builtin_amdgcn_rcpf(1.f + __expf(-x));
}
__device__ __forceinline__ float ftanh(float x){
  float ax = fabsf(x);
  float e  = __expf(2.f*ax);
  float r  = 1.f - 2.f*__builtin_amdgcn_rcpf(e+1.f);
  return copysignf(r, x);
}
__device__ __forceinline__ unsigned short f2bf(float f){
  __hip_bfloat16 b = __float2bfloat16(f);
  return __builtin_bit_cast(unsigned short, b);
}
__device__ __forceinline__ uint pk2(float a, float b){
  return (uint)f2bf(a) | ((uint)f2bf(b)<<16);
}

// K-1: init exchange buffer to bit0=1 (tag mismatch vs first expected tag 0;
// also rejects the 0xAA poison). Re-run every launch for determinism.
__global__ void zero_kernel(uint* __restrict__ exch){
  int i = blockIdx.x*blockDim.x + threadIdx.x;
  if (i < 2*EXHALF) exch[i] = 1u;
}

// K0: pre-gather x = bf16(emb[data]) : [B][L][128] bf16 (16 uint4 per row)
__global__ void xgather_kernel(const int* __restrict__ data, const float* __restrict__ emb,
                               uint4* __restrict__ xbf){
  int i = blockIdx.x*blockDim.x + threadIdx.x;   // NB*SL*16
  if (i >= NB*SL*16) return;
  int bt = i >> 4;
  int c  = i & 15;
  int token = data[bt];
  const float4* ep = (const float4*)(emb + (size_t)token*ED + c*8);
  float4 e0 = ep[0], e1 = ep[1];
  uint4 xv;
  xv.x = pk2(e0.x, e0.y); xv.y = pk2(e0.z, e0.w);
  xv.z = pk2(e1.x, e1.y); xv.w = pk2(e1.z, e1.w);
  xbf[(size_t)bt*16 + c] = xv;
}

// K1: persistent BiLSTM, parity-tagged lock-free h exchange (round-3 proven
// MALL protocol), with NG=4 independent batch-group chains interleaved per
// block to hide the MALL round trip: while chain g's store is in flight,
// chains g+1..g+3 compute. Grid 16 = 2dir x 8 unit-slices; cluster = the 8
// blocks of one dir. Per chain, per step: h stored in slot t&1 with bit0 tag
// (t>>1)&1 on every dword; consumer polls for the expected tag — data IS the
// flag. Safety per chain is the round-3 argument (consume(t-1) precedes
// produce(t) precedes any write of t+1); group interleave preserves per-chain
// program order, so the argument is unchanged.
__global__ __launch_bounds__(256, 1) void lstm_cluster(
    const uint4* __restrict__ xbf,
    const float* __restrict__ wihf, const float* __restrict__ whhf,
    const float* __restrict__ bihf, const float* __restrict__ bhhf,
    const float* __restrict__ wihb, const float* __restrict__ whhb,
    const float* __restrict__ bihb, const float* __restrict__ bhhb,
    uint* __restrict__ exch,
    uint* __restrict__ hf, uint* __restrict__ hb){
  const int tid  = threadIdx.x;
  const int lane = tid & 63;
  const int w    = tid >> 6;            // wave id == gate id (i,f,g,o)
  const int dir  = blockIdx.x >> 3;
  const int kblk = blockIdx.x & 7;      // unit slice [32*kblk, 32*kblk+32)

  __shared__ __align__(16) unsigned short xh[16*384]; // [b][k] bf16, XOR-swizzled
  __shared__ float gsm[128*17];                       // [row][batch] padded

  const float* Wih = dir ? wihb : wihf;
  const float* Whh = dir ? whhb : whhf;
  const float* Bih = dir ? bihb : bihf;
  const float* Bhh = dir ? bhhb : bhhf;

  // ---- one-time: weight B-fragments into registers ----
  short8 bfrag[2][12];
  float bias2[2];
  const int koff = (lane>>4)*8;
  #pragma unroll
  for (int tau=0; tau<2; ++tau){
    int ul = tau*16 + (lane&15);
    int R  = w*256 + kblk*32 + ul;
    bias2[tau] = Bih[R] + Bhh[R];
    #pragma unroll
    for (int s=0; s<12; ++s){
      const float* src = (s<4) ? (Wih + (size_t)R*ED + s*32 + koff)
                               : (Whh + (size_t)R*HD + (s-4)*32 + koff);
      float4 f0 = ((const float4*)src)[0];
      float4 f1 = ((const float4*)src)[1];
      short8 v;
      v[0]=(short)f2bf(f0.x); v[1]=(short)f2bf(f0.y);
      v[2]=(short)f2bf(f0.z); v[3]=(short)f2bf(f0.w);
      v[4]=(short)f2bf(f1.x); v[5]=(short)f2bf(f1.y);
      v[6]=(short)f2bf(f1.z); v[7]=(short)f2bf(f1.w);
      bfrag[tau][s] = v;
    }
  }

  const int sb = tid >> 4;          // staging batch (within group)
  const int sc = tid & 15;          // staging chunk
  const int ub = tid >> 4;          // update batch
  const int up = tid & 15;          // update unit-pair
  const int arow  = lane & 15;
  const int abase = arow*768 + (lane>>4)*16;
  const int aswz  = (arow & 7) << 4;
  char* xhb = (char*)xh;

  uint* hout = dir ? hb : hf;
  // per-group bases
  size_t exrd_base[NG], exwr_base[NG], xrow_base[NG];
  #pragma unroll
  for (int g=0; g<NG; ++g){
    exrd_base[g] = (size_t)((dir*4+g)*16 + sb)*128 + sc*8;
    exwr_base[g] = (size_t)((dir*4+g)*16 + ub)*128 + kblk*16 + up;
    xrow_base[g] = (size_t)(g*16+sb)*SL;
  }

  float creg0[NG], creg1[NG];
  #pragma unroll
  for (int g=0; g<NG; ++g){ creg0[g]=0.f; creg1[g]=0.f; }

  for (int t=0; t<SL; ++t){
    const int tt = dir ? (SL-1-t) : t;
    // prefetch all groups' x chunks (independent; hides global latency)
    uint4 xvg[NG];
    #pragma unroll
    for (int g=0; g<NG; ++g)
      xvg[g] = xbf[(xrow_base[g] + tt)*16 + sc];

    #pragma unroll 1
    for (int g=0; g<NG; ++g){
      // ---- h(t-1): poll parity-tagged exchange (MALL path) ----
      uintx4 h0v, h1v;
      if (t == 0){
        h0v = 0; h1v = 0;
      } else {
        const uint* exr = exch + (size_t)((t-1)&1)*EXHALF + exrd_base[g];
        const uint expect = ((uint)(t-1)>>1)&1u;
        uint hv[8];
        for (;;){
          uint ok = 1u;
          #pragma unroll
          for (int j=0;j<8;++j)
            hv[j] = __hip_atomic_load(exr+j, __ATOMIC_RELAXED, __HIP_MEMORY_SCOPE_AGENT);
          #pragma unroll
          for (int j=0;j<8;++j) ok &= (uint)((hv[j]&1u)==expect);
          if (ok) break;
        }
        h0v[0]=hv[0]&~1u; h0v[1]=hv[1]&~1u; h0v[2]=hv[2]&~1u; h0v[3]=hv[3]&~1u;
        h1v[0]=hv[4]&~1u; h1v[1]=hv[5]&~1u; h1v[2]=hv[6]&~1u; h1v[3]=hv[7]&~1u;
      }

      // ---- stage x + h into swizzled LDS ----
      *(uint4*)(xhb + ((sb*768 + sc*16) ^ ((sb&7)<<4))) = xvg[g];
      *(uintx4*)(xhb + ((sb*768 + 256 + sc*32)      ^ ((sb&7)<<4))) = h0v;
      *(uintx4*)(xhb + ((sb*768 + 256 + sc*32 + 16) ^ ((sb&7)<<4))) = h1v;
      __syncthreads();   // staging done; also orders prev group's gsm reads vs writes below

      // ---- MFMA: gates[16 batch][32 rows of this wave] ----
      floatx4 acc0; acc0[0]=bias2[0]; acc0[1]=bias2[0]; acc0[2]=bias2[0]; acc0[3]=bias2[0];
      floatx4 acc1; acc1[0]=bias2[1]; acc1[1]=bias2[1]; acc1[2]=bias2[1]; acc1[3]=bias2[1];
      #pragma unroll
      for (int s=0; s<12; ++s){
        short8 afrag = *(const short8*)(xhb + ((abase + s*64) ^ aswz));
        acc0 = __builtin_amdgcn_mfma_f32_16x16x32_bf16(afrag, bfrag[0][s], acc0, 0,0,0);
        acc1 = __builtin_amdgcn_mfma_f32_16x16x32_bf16(afrag, bfrag[1][s], acc1, 0,0,0);
      }
      {
        int gn = w*32 + (lane&15);
        int gm = (lane>>4)*4;
        #pragma unroll
        for (int j=0;j<4;++j){
          gsm[(gn   )*17 + gm + j] = acc0[j];
          gsm[(gn+16)*17 + gm + j] = acc1[j];
        }
      }
      __syncthreads();   // gsm ready; also orders MFMA xh reads vs next staging writes

      // ---- c/h update for units (2up, 2up+1), batch ub ----
      {
        int u0 = 2*up, u1 = 2*up+1;
        float gi0 = gsm[(0*32+u0)*17+ub], gf0 = gsm[(1*32+u0)*17+ub];
        float gg0 = gsm[(2*32+u0)*17+ub], go0 = gsm[(3*32+u0)*17+ub];
        float gi1 = gsm[(0*32+u1)*17+ub], gf1 = gsm[(1*32+u1)*17+ub];
        float gg1 = gsm[(2*32+u1)*17+ub], go1 = gsm[(3*32+u1)*17+ub];
        float c0 = fsig(gf0)*creg0[g] + fsig(gi0)*ftanh(gg0); creg0[g] = c0;
        float c1 = fsig(gf1)*creg1[g] + fsig(gi1)*ftanh(gg1); creg1[g] = c1;
        float h0f = fsig(go0)*ftanh(c0);
        float h1f = fsig(go1)*ftanh(c1);
        uint hpack = pk2(h0f, h1f);
        uint exv = (hpack & ~1u) | ((uint)(t>>1)&1u);   // parity tag in bit0
        uint* exw = exch + (size_t)(t&1)*EXHALF + exwr_base[g];
        __hip_atomic_store(exw, exv, __ATOMIC_RELAXED, __HIP_MEMORY_SCOPE_AGENT);
        hout[((size_t)(g*16+ub)*SL + tt)*128 + kblk*16 + up] = hpack;
      }
      // no end barrier: next group's first sync orders gsm reads vs next writes.
    }
  }
}

// K2: emission GEMM via MFMA: [65536 rows x 512] @ [512 x 48(35)] -> emis fp32.
// 512 blocks x 256 thr (4 waves). Block: 128 rows; cls_w bf16 staged in LDS.
__global__ __launch_bounds__(256) void emis_mfma(
    const unsigned short* __restrict__ hfu, const unsigned short* __restrict__ hbu,
    const float* __restrict__ clsw, const float* __restrict__ clsb,
    float* __restrict__ emis){
  __shared__ unsigned short wsm[48*520];                // bf16 [48][520], 512 used
  __shared__ __align__(16) unsigned short alds[128*40]; // [128][40] u16 (80B pitch)
  const int tid = threadIdx.x;
  const int lane = tid & 63;
  const int wid  = tid >> 6;
  for (int i=tid; i<6144; i+=256){
    int r = i >> 7, c4 = (i & 127)*4;
    uint2 pv;
    if (r < 35){
      float4 v = *(const float4*)(clsw + (size_t)r*512 + c4);
      pv.x = pk2(v.x, v.y); pv.y = pk2(v.z, v.w);
    } else { pv.x = 0u; pv.y = 0u; }
    *(uint2*)(wsm + r*520 + c4) = pv;
  }
  __syncthreads();
  floatx4 acc[2][3];
  #pragma unroll
  for (int mt=0;mt<2;++mt)
    #pragma unroll
    for (int nt=0;nt<3;++nt){ acc[mt][nt][0]=0;acc[mt][nt][1]=0;acc[mt][nt][2]=0;acc[mt][nt][3]=0; }

  const size_t row0 = (size_t)blockIdx.x*128;
  for (int ks=0; ks<16; ++ks){
    const unsigned short* hsrc = (ks<8) ? hfu : hbu;
    const int col = (ks&7)*32;
    __syncthreads();
    #pragma unroll
    for (int q=0;q<2;++q){
      int j = tid*2+q;           // 0..511
      int r = j>>2, c4 = j&3;
      uint4 v = *(const uint4*)(hsrc + (row0 + r)*256 + col + c4*8);
      *(uint4*)((char*)alds + r*80 + c4*16) = v;
    }
    __syncthreads();
    short8 bf[3];
    #pragma unroll
    for (int nt=0;nt<3;++nt){
      int rr = nt*16 + (lane&15);
      bf[nt] = *(const short8*)(wsm + rr*520 + ks*32 + (lane>>4)*8);
    }
    #pragma unroll
    for (int mt=0;mt<2;++mt){
      int r = (wid*2+mt)*16 + (lane&15);
      short8 af = *(const short8*)((char*)alds + r*80 + (lane>>4)*16);
      #pragma unroll
      for (int nt=0;nt<3;++nt)
        acc[mt][nt] = __builtin_amdgcn_mfma_f32_16x16x32_bf16(af, bf[nt], acc[mt][nt], 0,0,0);
    }
  }
  #pragma unroll
  for (int mt=0;mt<2;++mt){
    #pragma unroll
    for (int nt=0;nt<3;++nt){
      int tag = nt*16 + (lane&15);
      if (tag < NT){
        float bv = clsb[tag];
        #pragma unroll
        for (int j=0;j<4;++j){
          int m = (wid*2+mt)*16 + (lane>>4)*4 + j;
          emis[(row0 + m)*NT + tag] = acc[mt][nt][j] + bv;
        }
      }
    }
  }
}

// K3: gold score + CRF forward. 1 wave per batch, wave-synchronous (no barriers),
// E rows in registers, aL in LDS (broadcast reads), 4-way dot chains.
__global__ void crf_kernel(const float* __restrict__ emis, const float* __restrict__ trans,
                           const int* __restrict__ tags, float* __restrict__ diff){
  const int b = blockIdx.x, l = threadIdx.x;   // 64 threads = 1 wave
  __shared__ float aLds[64];
  float gp = 0.f;
  for (int t=l; t<SL; t+=64){
    int tg = tags[b*SL+t];
    int pv = (t>0) ? tags[b*SL+t-1] : TSTART;
    gp += emis[((size_t)(b*SL)+t)*NT + tg] + trans[tg*NT+pv];
  }
  #pragma unroll
  for (int m=1;m<64;m<<=1) gp += __shfl_xor(gp, m);
  float Erow[NT];
  #pragma unroll
  for (int p=0;p<NT;++p) Erow[p] = (l<NT) ? __expf(trans[l*NT+p]) : 0.f;
  aLds[l] = (l==TSTART) ? 1.f : 0.f;
  float logZ = 0.f;
  const float* ep = emis + (size_t)b*SL*NT;
  float epre = (l<NT) ? ep[l] : 0.f;
  for (int t=0; t<SL; ++t){
    float ev = __expf(epre);
    int tn = (t+1 < SL) ? (t+1) : (SL-1);
    epre = (l<NT) ? ep[(size_t)tn*NT + l] : 0.f;
    float s0=0.f, s1=0.f, s2=0.f, s3=0.f;
    #pragma unroll
    for (int p=0;p<32;p+=4){
      s0 += Erow[p  ]*aLds[p  ];
      s1 += Erow[p+1]*aLds[p+1];
      s2 += Erow[p+2]*aLds[p+2];
      s3 += Erow[p+3]*aLds[p+3];
    }
    s0 += Erow[32]*aLds[32];
    s1 += Erow[33]*aLds[33];
    s2 += Erow[34]*aLds[34];
    float v = ((s0+s1)+(s2+s3)) * ev;      // lanes >= NT: 0
    float tot = v;
    #pragma unroll
    for (int m=1;m<64;m<<=1) tot += __shfl_xor(tot, m);
    logZ += __logf(tot);
    aLds[l] = v * __builtin_amdgcn_rcpf(tot);   // wave-order LDS: next reads see this
  }
  if (l == 0) diff[b] = logZ - gp;
}

// K4: loss = mean(diff)
__global__ void final_kernel(const float* __restrict__ diff, float* __restrict__ out){
  int l = threadIdx.x;
  float v = diff[l];
  #pragma unroll
  for (int m=1;m<64;m<<=1) v += __shfl_xor(v, m);
  if (l == 0) out[0] = v * (1.f/64.f);
}

extern "C" void kernel_launch(void* const* d_in, const int* in_sizes, int n_in,
                              void* d_out, int out_size, void* d_ws, size_t ws_size,
                              hipStream_t stream){
  const int*   data = (const int*)d_in[0];
  const int*   tags = (const int*)d_in[2];
  const float* emb  = (const float*)d_in[3];
  const float* wihf = (const float*)d_in[4];
  const float* whhf = (const float*)d_in[5];
  const float* bihf = (const float*)d_in[6];
  const float* bhhf = (const float*)d_in[7];
  const float* wihb = (const float*)d_in[8];
  const float* whhb = (const float*)d_in[9];
  const float* bihb = (const float*)d_in[10];
  const float* bhhb = (const float*)d_in[11];
  const float* clsw = (const float*)d_in[12];
  const float* clsb = (const float*)d_in[13];
  const float* trans= (const float*)d_in[14];

  char* ws = (char*)d_ws;
  uint*  hf    = (uint*)(ws);                    // 33,554,432 B (bf16 [B][L][256])
  uint*  hb    = (uint*)(ws + 33554432);         // 33,554,432 B
  uint4* xbf   = (uint4*)(ws + 67108864);        // 16,777,216 B (bf16 x, lstm-only)
  float* emis  = (float*)(ws + 67108864);        //  9,175,040 B (overlays xbf post-lstm)
  uint*  exch  = (uint*)(ws + 83886080);         //    131,072 B (MALL exchange)
  float* diff  = (float*)(ws + 84017152);        //        256 B
  float* out   = (float*)d_out;

  zero_kernel<<<dim3(128), dim3(256), 0, stream>>>(exch);
  xgather_kernel<<<dim3(4096), dim3(256), 0, stream>>>(data, emb, xbf);
  lstm_cluster<<<dim3(16), dim3(256), 0, stream>>>(
      xbf, wihf, whhf, bihf, bhhf, wihb, whhb, bihb, bhhb,
      exch, hf, hb);
  emis_mfma<<<dim3(512), dim3(256), 0, stream>>>(
      (const unsigned short*)hf, (const unsigned short*)hb, clsw, clsb, emis);
  crf_kernel<<<dim3(64), dim3(64), 0, stream>>>(emis, trans, tags, diff);
  final_kernel<<<dim3(1), dim3(64), 0, stream>>>(diff, out);
}

// Round 6
// 4030.462 us; speedup vs baseline: 9.0952x; 2.6135x over previous
//
#include <hip/hip_runtime.h>
#include <hip/hip_bf16.h>
#include <cstdint>

#define NB 64      // batch
#define SL 1024    // seq len
#define ED 128     // embed
#define HD 256     // hidden
#define NT 35      // tags
#define TSTART 33

typedef unsigned int uint;
typedef __attribute__((ext_vector_type(8))) short short8;
typedef __attribute__((ext_vector_type(4))) float floatx4;

__device__ __forceinline__ float fsig(float x){
  return __builtin_amdgcn_rcpf(1.f + __expf(-x));
}
__device__ __forceinline__ float ftanh(float x){
  float ax = fabsf(x);
  float e  = __expf(2.f*ax);
  float r  = 1.f - 2.f*__builtin_amdgcn_rcpf(e+1.f);
  return copysignf(r, x);
}
__device__ __forceinline__ unsigned short f2bf(float f){
  __hip_bfloat16 b = __float2bfloat16(f);
  return __builtin_bit_cast(unsigned short, b);
}
__device__ __forceinline__ uint pk2(float a, float b){
  return (uint)f2bf(a) | ((uint)f2bf(b)<<16);
}
__device__ __forceinline__ void unpack8(uint4 w, float* f){
  f[0]=__uint_as_float(w.x<<16); f[1]=__uint_as_float(w.x&0xffff0000u);
  f[2]=__uint_as_float(w.y<<16); f[3]=__uint_as_float(w.y&0xffff0000u);
  f[4]=__uint_as_float(w.z<<16); f[5]=__uint_as_float(w.z&0xffff0000u);
  f[6]=__uint_as_float(w.w<<16); f[7]=__uint_as_float(w.w&0xffff0000u);
}

// ---- fp8 e4m3 (OCP) encode: builtin if available, manual fallback ----
__device__ __forceinline__ uint enc_e4m3(float f){
  uint s = (__float_as_uint(f) >> 24) & 0x80u;
  float a = fabsf(f);
  if (a >= 448.f) return s | 0x7Eu;
  if (a < 0.0009765625f) return s;            // < 2^-10 -> 0
  int e; float m = frexpf(a, &e);             // a = m*2^e, m in [0.5,1)
  int E = e + 6;                              // biased exponent of (2m)*2^(e-1)
  if (E >= 1){
    uint mb = (uint)rintf(m*16.f);            // in [8,16]
    if (mb >= 16u){ E += 1; mb = 8u; }
    if (E > 15) return s | 0x7Eu;
    return s | ((uint)E<<3) | (mb - 8u);
  } else {
    uint mb = (uint)rintf(a*512.f);
    if (mb > 7u) return s | 0x08u;
    return s | mb;
  }
}
__device__ __forceinline__ uint cvt2(float a, float b){
#if __has_builtin(__builtin_amdgcn_cvt_pk_fp8_f32)
  return ((uint)__builtin_amdgcn_cvt_pk_fp8_f32(a, b, 0, false)) & 0xFFFFu;
#else
  return enc_e4m3(a) | (enc_e4m3(b)<<8);
#endif
}

// K0: pre-gather x = fp8(emb[data]) : [B*L][32] dwords (128 fp8/row)
__global__ void xgather8(const int* __restrict__ data, const float* __restrict__ emb,
                         uint* __restrict__ xf8){
  int i = blockIdx.x*blockDim.x + threadIdx.x;   // NB*SL*32
  if (i >= NB*SL*32) return;
  int bt = i >> 5;
  int c  = i & 31;
  int token = data[bt];
  float4 e = ((const float4*)(emb + (size_t)token*ED + c*4))[0];
  xf8[i] = cvt2(e.x, e.y) | (cvt2(e.z, e.w) << 16);
}

// K1: zero-exchange BiLSTM. Grid 8 = 2dir x 4 batch-groups(16); 512 threads
// (8 waves). Each block holds the ENTIRE per-direction weight set as fp8
// MFMA B-fragments in registers (W scaled x16 -> e4m3 normal range; gates
// recovered as acc/16 + fp32 bias). h and x live in double-buffered LDS as
// fp8 A tiles [16 batch][408B pitch: 128 x | 256 h]. Per step: 768 fp8 MFMAs
// + in-register nonlinearity + ONE __syncthreads. No inter-block traffic.
// Wave w owns units [w*32, w*32+32) as 2 chunks of 16; lane: n15=unit-in-tile,
// kg=k-group; D[m][n]: n=lane&15 (unit), m=(lane>>4)*4+j (batch).
__global__ __launch_bounds__(512, 2) void lstm_block(
    const uint* __restrict__ xf8,
    const float* __restrict__ wihf, const float* __restrict__ whhf,
    const float* __restrict__ bihf, const float* __restrict__ bhhf,
    const float* __restrict__ wihb, const float* __restrict__ whhb,
    const float* __restrict__ bihb, const float* __restrict__ bhhb,
    unsigned short* __restrict__ hf, unsigned short* __restrict__ hb){
  const int tid  = threadIdx.x;
  const int lane = tid & 63;
  const int w    = tid >> 6;          // wave 0..7
  const int dir  = blockIdx.x >> 2;
  const int bg   = blockIdx.x & 3;
  const int b0   = bg*16;

  __shared__ __align__(16) unsigned char Ab[2][16*408];

  const float* Wih = dir ? wihb : wihf;
  const float* Whh = dir ? whhb : whhf;
  const float* Bih = dir ? bihb : bihf;
  const float* Bhh = dir ? bhhb : bhhf;
  unsigned short* hout = dir ? hb : hf;

  const int n15 = lane & 15;
  const int kg  = lane >> 4;          // 0..3

  // ---- one-time: full weight residency as fp8(16W) B-fragments ----
  long long wfr[2][4][12];
  float bias16[2][4];
  #pragma unroll
  for (int cc=0; cc<2; ++cc){
    #pragma unroll
    for (int gt=0; gt<4; ++gt){
      int R = gt*256 + w*32 + cc*16 + n15;
      bias16[cc][gt] = 16.f*(Bih[R] + Bhh[R]);
      #pragma unroll
      for (int kt=0; kt<12; ++kt){
        int k0 = kt*32 + kg*8;
        const float* src = (kt<4) ? (Wih + (size_t)R*ED + k0)
                                  : (Whh + (size_t)R*HD + (k0-128));
        float4 f0 = ((const float4*)src)[0];
        float4 f1 = ((const float4*)src)[1];
        uint2 p;
        p.x = cvt2(16.f*f0.x, 16.f*f0.y) | (cvt2(16.f*f0.z, 16.f*f0.w) << 16);
        p.y = cvt2(16.f*f1.x, 16.f*f1.y) | (cvt2(16.f*f1.z, 16.f*f1.w) << 16);
        wfr[cc][gt][kt] = __builtin_bit_cast(long long, p);
      }
    }
  }

  float cst[2][4];
  #pragma unroll
  for (int cc=0; cc<2; ++cc)
    #pragma unroll
    for (int j=0; j<4; ++j) cst[cc][j] = 0.f;

  // ---- prologue: zero h region of buf0; stage x(0) into buf0 ----
  const int sb = tid >> 5, sdw = tid & 31;   // staging: batch, dword
  *(uint2*)(&Ab[0][sb*408 + 128 + sdw*8]) = (uint2){0u, 0u};
  {
    int tt0 = dir ? (SL-1) : 0;
    uint xv = xf8[((size_t)(b0+sb)*SL + tt0)*32 + sdw];
    *(uint*)(&Ab[0][sb*408 + sdw*4]) = xv;
  }
  __syncthreads();

  for (int t=0; t<SL; ++t){
    const int cur = t & 1, nxt = cur ^ 1;
    const int tt  = dir ? (SL-1-t) : t;

    // stage x(t+1) into nxt (x region, disjoint from h region)
    if (t+1 < SL){
      int tt1 = dir ? (SL-2-t) : (t+1);
      uint xv = xf8[((size_t)(b0+sb)*SL + tt1)*32 + sdw];
      *(uint*)(&Ab[nxt][sb*408 + sdw*4]) = xv;
    }

    const unsigned char* Ac = Ab[cur];
    #pragma unroll
    for (int cc=0; cc<2; ++cc){
      floatx4 acc[4];
      #pragma unroll
      for (int gt=0; gt<4; ++gt){
        float bv = bias16[cc][gt];
        acc[gt][0]=bv; acc[gt][1]=bv; acc[gt][2]=bv; acc[gt][3]=bv;
      }
      #pragma unroll
      for (int kt=0; kt<12; ++kt){
        long long la = *(const long long*)(Ac + n15*408 + kt*32 + kg*8);
        #pragma unroll
        for (int gt=0; gt<4; ++gt)
          acc[gt] = __builtin_amdgcn_mfma_f32_16x16x32_fp8_fp8(
                        la, wfr[cc][gt][kt], acc[gt], 0, 0, 0);
      }
      const int unit = w*32 + cc*16 + n15;
      #pragma unroll
      for (int j=0; j<4; ++j){
        const int bb = kg*4 + j;
        float gi = acc[0][j]*0.0625f, gf = acc[1][j]*0.0625f;
        float gg = acc[2][j]*0.0625f, go = acc[3][j]*0.0625f;
        float c  = fsig(gf)*cst[cc][j] + fsig(gi)*ftanh(gg);
        cst[cc][j] = c;
        float h  = fsig(go)*ftanh(c);
        Ab[nxt][bb*408 + 128 + unit] = (unsigned char)(cvt2(h, 0.f) & 0xFFu);
        hout[((size_t)(b0+bb)*SL + tt)*256 + unit] = f2bf(h);
      }
    }
    __syncthreads();   // orders: reads(cur) & writes(nxt) vs next iteration
  }
}

// K2: emission GEMM via MFMA: [65536 rows x 512] @ [512 x 48(35)] -> emis fp32.
__global__ __launch_bounds__(256) void emis_mfma(
    const unsigned short* __restrict__ hfu, const unsigned short* __restrict__ hbu,
    const float* __restrict__ clsw, const float* __restrict__ clsb,
    float* __restrict__ emis){
  __shared__ unsigned short wsm[48*520];                // bf16 [48][520], 512 used
  __shared__ __align__(16) unsigned short alds[128*40]; // [128][40] u16 (80B pitch)
  const int tid = threadIdx.x;
  const int lane = tid & 63;
  const int wid  = tid >> 6;
  for (int i=tid; i<6144; i+=256){
    int r = i >> 7, c4 = (i & 127)*4;
    uint2 pv;
    if (r < 35){
      float4 v = *(const float4*)(clsw + (size_t)r*512 + c4);
      pv.x = pk2(v.x, v.y); pv.y = pk2(v.z, v.w);
    } else { pv.x = 0u; pv.y = 0u; }
    *(uint2*)(wsm + r*520 + c4) = pv;
  }
  __syncthreads();
  floatx4 acc[2][3];
  #pragma unroll
  for (int mt=0;mt<2;++mt)
    #pragma unroll
    for (int nt=0;nt<3;++nt){ acc[mt][nt][0]=0;acc[mt][nt][1]=0;acc[mt][nt][2]=0;acc[mt][nt][3]=0; }

  const size_t row0 = (size_t)blockIdx.x*128;
  for (int ks=0; ks<16; ++ks){
    const unsigned short* hsrc = (ks<8) ? hfu : hbu;
    const int col = (ks&7)*32;
    __syncthreads();
    #pragma unroll
    for (int q=0;q<2;++q){
      int j = tid*2+q;           // 0..511
      int r = j>>2, c4 = j&3;
      uint4 v = *(const uint4*)(hsrc + (row0 + r)*256 + col + c4*8);
      *(uint4*)((char*)alds + r*80 + c4*16) = v;
    }
    __syncthreads();
    short8 bf[3];
    #pragma unroll
    for (int nt=0;nt<3;++nt){
      int rr = nt*16 + (lane&15);
      bf[nt] = *(const short8*)(wsm + rr*520 + ks*32 + (lane>>4)*8);
    }
    #pragma unroll
    for (int mt=0;mt<2;++mt){
      int r = (wid*2+mt)*16 + (lane&15);
      short8 af = *(const short8*)((char*)alds + r*80 + (lane>>4)*16);
      #pragma unroll
      for (int nt=0;nt<3;++nt)
        acc[mt][nt] = __builtin_amdgcn_mfma_f32_16x16x32_bf16(af, bf[nt], acc[mt][nt], 0,0,0);
    }
  }
  #pragma unroll
  for (int mt=0;mt<2;++mt){
    #pragma unroll
    for (int nt=0;nt<3;++nt){
      int tag = nt*16 + (lane&15);
      if (tag < NT){
        float bv = clsb[tag];
        #pragma unroll
        for (int j=0;j<4;++j){
          int m = (wid*2+mt)*16 + (lane>>4)*4 + j;
          emis[(row0 + m)*NT + tag] = acc[mt][nt][j] + bv;
        }
      }
    }
  }
}

// K3: gold score + CRF forward. 1 wave per batch, wave-synchronous.
__global__ void crf_kernel(const float* __restrict__ emis, const float* __restrict__ trans,
                           const int* __restrict__ tags, float* __restrict__ diff){
  const int b = blockIdx.x, l = threadIdx.x;   // 64 threads = 1 wave
  __shared__ float aLds[64];
  float gp = 0.f;
  for (int t=l; t<SL; t+=64){
    int tg = tags[b*SL+t];
    int pv = (t>0) ? tags[b*SL+t-1] : TSTART;
    gp += emis[((size_t)(b*SL)+t)*NT + tg] + trans[tg*NT+pv];
  }
  #pragma unroll
  for (int m=1;m<64;m<<=1) gp += __shfl_xor(gp, m);
  float Erow[NT];
  #pragma unroll
  for (int p=0;p<NT;++p) Erow[p] = (l<NT) ? __expf(trans[l*NT+p]) : 0.f;
  aLds[l] = (l==TSTART) ? 1.f : 0.f;
  float logZ = 0.f;
  const float* ep = emis + (size_t)b*SL*NT;
  float epre = (l<NT) ? ep[l] : 0.f;
  for (int t=0; t<SL; ++t){
    float ev = __expf(epre);
    int tn = (t+1 < SL) ? (t+1) : (SL-1);
    epre = (l<NT) ? ep[(size_t)tn*NT + l] : 0.f;
    float s0=0.f, s1=0.f, s2=0.f, s3=0.f;
    #pragma unroll
    for (int p=0;p<32;p+=4){
      s0 += Erow[p  ]*aLds[p  ];
      s1 += Erow[p+1]*aLds[p+1];
      s2 += Erow[p+2]*aLds[p+2];
      s3 += Erow[p+3]*aLds[p+3];
    }
    s0 += Erow[32]*aLds[32];
    s1 += Erow[33]*aLds[33];
    s2 += Erow[34]*aLds[34];
    float v = ((s0+s1)+(s2+s3)) * ev;      // lanes >= NT: 0
    float tot = v;
    #pragma unroll
    for (int m=1;m<64;m<<=1) tot += __shfl_xor(tot, m);
    logZ += __logf(tot);
    aLds[l] = v * __builtin_amdgcn_rcpf(tot);   // wave-order LDS
  }
  if (l == 0) diff[b] = logZ - gp;
}

// K4: loss = mean(diff)
__global__ void final_kernel(const float* __restrict__ diff, float* __restrict__ out){
  int l = threadIdx.x;
  float v = diff[l];
  #pragma unroll
  for (int m=1;m<64;m<<=1) v += __shfl_xor(v, m);
  if (l == 0) out[0] = v * (1.f/64.f);
}

extern "C" void kernel_launch(void* const* d_in, const int* in_sizes, int n_in,
                              void* d_out, int out_size, void* d_ws, size_t ws_size,
                              hipStream_t stream){
  const int*   data = (const int*)d_in[0];
  const int*   tags = (const int*)d_in[2];
  const float* emb  = (const float*)d_in[3];
  const float* wihf = (const float*)d_in[4];
  const float* whhf = (const float*)d_in[5];
  const float* bihf = (const float*)d_in[6];
  const float* bhhf = (const float*)d_in[7];
  const float* wihb = (const float*)d_in[8];
  const float* whhb = (const float*)d_in[9];
  const float* bihb = (const float*)d_in[10];
  const float* bhhb = (const float*)d_in[11];
  const float* clsw = (const float*)d_in[12];
  const float* clsb = (const float*)d_in[13];
  const float* trans= (const float*)d_in[14];

  char* ws = (char*)d_ws;
  unsigned short* hf = (unsigned short*)(ws);            // 33,554,432 B
  unsigned short* hb = (unsigned short*)(ws + 33554432); // 33,554,432 B
  uint*  xf8  = (uint*)(ws + 67108864);                  //  8,388,608 B (lstm-only)
  float* emis = (float*)(ws + 67108864);                 //  9,175,040 B (overlays xf8 post-lstm)
  float* diff = (float*)(ws + 76283904);                 //        256 B
  float* out  = (float*)d_out;

  xgather8<<<dim3(8192), dim3(256), 0, stream>>>(data, emb, xf8);
  lstm_block<<<dim3(8), dim3(512), 0, stream>>>(
      xf8, wihf, whhf, bihf, bhhf, wihb, whhb, bihb, bhhb, hf, hb);
  emis_mfma<<<dim3(512), dim3(256), 0, stream>>>(hf, hb, clsw, clsb, emis);
  crf_kernel<<<dim3(64), dim3(64), 0, stream>>>(emis, trans, tags, diff);
  final_kernel<<<dim3(1), dim3(64), 0, stream>>>(diff, out);
}

// Round 7
// 3458.370 us; speedup vs baseline: 10.5997x; 1.1654x over previous
//
#include <hip/hip_runtime.h>
#include <hip/hip_bf16.h>
#include <cstdint>

#define NB 64      // batch
#define SL 1024    // seq len
#define ED 128     // embed
#define HD 256     // hidden
#define NT 35      // tags
#define TSTART 33

typedef unsigned int uint;
typedef __attribute__((ext_vector_type(8))) short short8;
typedef __attribute__((ext_vector_type(4))) float floatx4;

__device__ __forceinline__ float fsig(float x){
  return __builtin_amdgcn_rcpf(1.f + __expf(-x));
}
__device__ __forceinline__ float ftanh(float x){
  float ax = fabsf(x);
  float e  = __expf(2.f*ax);
  float r  = 1.f - 2.f*__builtin_amdgcn_rcpf(e+1.f);
  return copysignf(r, x);
}
__device__ __forceinline__ unsigned short f2bf(float f){
  __hip_bfloat16 b = __float2bfloat16(f);
  return __builtin_bit_cast(unsigned short, b);
}
__device__ __forceinline__ uint pk2(float a, float b){
  return (uint)f2bf(a) | ((uint)f2bf(b)<<16);
}

// ---- fp8 e4m3 (OCP) encode: builtin if available, manual fallback ----
__device__ __forceinline__ uint enc_e4m3(float f){
  uint s = (__float_as_uint(f) >> 24) & 0x80u;
  float a = fabsf(f);
  if (a >= 448.f) return s | 0x7Eu;
  if (a < 0.0009765625f) return s;
  int e; float m = frexpf(a, &e);
  int E = e + 6;
  if (E >= 1){
    uint mb = (uint)rintf(m*16.f);
    if (mb >= 16u){ E += 1; mb = 8u; }
    if (E > 15) return s | 0x7Eu;
    return s | ((uint)E<<3) | (mb - 8u);
  } else {
    uint mb = (uint)rintf(a*512.f);
    if (mb > 7u) return s | 0x08u;
    return s | mb;
  }
}
__device__ __forceinline__ uint cvt2(float a, float b){
#if __has_builtin(__builtin_amdgcn_cvt_pk_fp8_f32)
  return ((uint)__builtin_amdgcn_cvt_pk_fp8_f32(a, b, 0, false)) & 0xFFFFu;
#else
  return enc_e4m3(a) | (enc_e4m3(b)<<8);
#endif
}

// K0: pre-gather x = fp8(emb[data]) : [B*L][32] dwords (128 fp8/row)
__global__ void xgather8(const int* __restrict__ data, const float* __restrict__ emb,
                         uint* __restrict__ xf8){
  int i = blockIdx.x*blockDim.x + threadIdx.x;   // NB*SL*32
  if (i >= NB*SL*32) return;
  int bt = i >> 5;
  int c  = i & 31;
  int token = data[bt];
  float4 e = ((const float4*)(emb + (size_t)token*ED + c*4))[0];
  xf8[i] = cvt2(e.x, e.y) | (cvt2(e.z, e.w) << 16);
}

// K1: zero-exchange BiLSTM (round-6 structure) with the spill fixed:
//  - W_hh fragments (64 longs = 128 VGPR) stay in registers;
//  - W_ih fragments move to LDS as THREAD-PRIVATE slots (128 KB): each thread
//    reads back only what it wrote -> no barrier needed, conflict-free b64.
//    Register demand drops ~280 -> ~190 (<=256), and 144 KB LDS forces
//    1 block/CU so the allocator has no incentive to squeeze to 128 VGPR.
//  - raw barrier (lgkmcnt only, NO vmcnt drain): h global stores stay in
//    flight across steps instead of draining at every __syncthreads.
//  - x(t+1) global load issued at step top, ds_written at step bottom: its
//    ~300-600cy latency hides under the MFMA phase.
__global__ __launch_bounds__(512, 2) void lstm_block(
    const uint* __restrict__ xf8,
    const float* __restrict__ wihf, const float* __restrict__ whhf,
    const float* __restrict__ bihf, const float* __restrict__ bhhf,
    const float* __restrict__ wihb, const float* __restrict__ whhb,
    const float* __restrict__ bihb, const float* __restrict__ bhhb,
    unsigned short* __restrict__ hf, unsigned short* __restrict__ hb){
  const int tid  = threadIdx.x;
  const int lane = tid & 63;
  const int w    = tid >> 6;          // wave 0..7
  const int dir  = blockIdx.x >> 2;
  const int bg   = blockIdx.x & 3;
  const int b0   = bg*16;

  __shared__ __align__(16) unsigned char WihL[131072]; // [w][cc][gt][kt][lane] b64 frags
  __shared__ __align__(16) unsigned char Ab[2][16*408];

  const float* Wih = dir ? wihb : wihf;
  const float* Whh = dir ? whhb : whhf;
  const float* Bih = dir ? bihb : bihf;
  const float* Bhh = dir ? bhhb : bhhf;
  unsigned short* hout = dir ? hb : hf;

  const int n15 = lane & 15;
  const int kg  = lane >> 4;          // 0..3

  // ---- one-time: W_ih -> fp8(16W) frags in LDS (thread-private slots) ----
  #pragma unroll
  for (int cc=0; cc<2; ++cc){
    #pragma unroll
    for (int gt=0; gt<4; ++gt){
      int R = gt*256 + w*32 + cc*16 + n15;
      #pragma unroll
      for (int kt=0; kt<4; ++kt){
        const float* src = Wih + (size_t)R*ED + kt*32 + kg*8;
        float4 f0 = ((const float4*)src)[0];
        float4 f1 = ((const float4*)src)[1];
        uint2 p;
        p.x = cvt2(16.f*f0.x, 16.f*f0.y) | (cvt2(16.f*f0.z, 16.f*f0.w) << 16);
        p.y = cvt2(16.f*f1.x, 16.f*f1.y) | (cvt2(16.f*f1.z, 16.f*f1.w) << 16);
        int slot = ((((w*2+cc)*4+gt)*4+kt)<<9) + lane*8;
        *(uint2*)(WihL + slot) = p;
      }
    }
  }
  // ---- one-time: W_hh -> fp8(16W) frags in registers (64 longs = 128 VGPR) ----
  long long whhR[2][4][8];
  float bias16[2][4];
  #pragma unroll
  for (int cc=0; cc<2; ++cc){
    #pragma unroll
    for (int gt=0; gt<4; ++gt){
      int R = gt*256 + w*32 + cc*16 + n15;
      bias16[cc][gt] = 16.f*(Bih[R] + Bhh[R]);
      #pragma unroll
      for (int kt=0; kt<8; ++kt){
        const float* src = Whh + (size_t)R*HD + kt*32 + kg*8;
        float4 f0 = ((const float4*)src)[0];
        float4 f1 = ((const float4*)src)[1];
        uint2 p;
        p.x = cvt2(16.f*f0.x, 16.f*f0.y) | (cvt2(16.f*f0.z, 16.f*f0.w) << 16);
        p.y = cvt2(16.f*f1.x, 16.f*f1.y) | (cvt2(16.f*f1.z, 16.f*f1.w) << 16);
        whhR[cc][gt][kt] = __builtin_bit_cast(long long, p);
      }
    }
  }

  float cst[2][4];
  #pragma unroll
  for (int cc=0; cc<2; ++cc)
    #pragma unroll
    for (int j=0; j<4; ++j) cst[cc][j] = 0.f;

  // ---- prologue: zero h region of buf0; stage x(0) into buf0 ----
  const int sb = tid >> 5, sdw = tid & 31;   // staging: batch, dword
  *(uint2*)(&Ab[0][sb*408 + 128 + sdw*8]) = (uint2){0u, 0u};
  {
    int tt0 = dir ? (SL-1) : 0;
    uint xv = xf8[((size_t)(b0+sb)*SL + tt0)*32 + sdw];
    *(uint*)(&Ab[0][sb*408 + sdw*4]) = xv;
  }
  __syncthreads();

  for (int t=0; t<SL; ++t){
    const int cur = t & 1, nxt = cur ^ 1;
    const int tt  = dir ? (SL-1-t) : t;

    // issue x(t+1) load NOW; consume at step bottom (latency under MFMAs)
    uint xv = 0;
    if (t+1 < SL){
      int tt1 = dir ? (SL-2-t) : (t+1);
      xv = xf8[((size_t)(b0+sb)*SL + tt1)*32 + sdw];
    }

    const unsigned char* Ac = Ab[cur];
    #pragma unroll
    for (int cc=0; cc<2; ++cc){
      floatx4 acc[4];
      #pragma unroll
      for (int gt=0; gt<4; ++gt){
        float bv = bias16[cc][gt];
        acc[gt][0]=bv; acc[gt][1]=bv; acc[gt][2]=bv; acc[gt][3]=bv;
      }
      // x part: W_ih frags from (thread-private) LDS
      #pragma unroll
      for (int kt=0; kt<4; ++kt){
        long long la = *(const long long*)(Ac + n15*408 + kt*32 + kg*8);
        #pragma unroll
        for (int gt=0; gt<4; ++gt){
          long long wb = *(const long long*)(WihL + ((((w*2+cc)*4+gt)*4+kt)<<9) + lane*8);
          acc[gt] = __builtin_amdgcn_mfma_f32_16x16x32_fp8_fp8(la, wb, acc[gt], 0,0,0);
        }
      }
      // h part: W_hh frags from registers
      #pragma unroll
      for (int kt=0; kt<8; ++kt){
        long long la = *(const long long*)(Ac + n15*408 + 128 + kt*32 + kg*8);
        #pragma unroll
        for (int gt=0; gt<4; ++gt)
          acc[gt] = __builtin_amdgcn_mfma_f32_16x16x32_fp8_fp8(la, whhR[cc][gt][kt], acc[gt], 0,0,0);
      }
      const int unit = w*32 + cc*16 + n15;
      #pragma unroll
      for (int j=0; j<4; ++j){
        const int bb = kg*4 + j;
        float gi = acc[0][j]*0.0625f, gf = acc[1][j]*0.0625f;
        float gg = acc[2][j]*0.0625f, go = acc[3][j]*0.0625f;
        float c  = fsig(gf)*cst[cc][j] + fsig(gi)*ftanh(gg);
        cst[cc][j] = c;
        float h  = fsig(go)*ftanh(c);
        Ab[nxt][bb*408 + 128 + unit] = (unsigned char)(cvt2(h, 0.f) & 0xFFu);
        hout[((size_t)(b0+bb)*SL + tt)*256 + unit] = f2bf(h);
      }
    }
    // consume the prefetched x(t+1)
    if (t+1 < SL) *(uint*)(&Ab[nxt][sb*408 + sdw*4]) = xv;
    // raw barrier: order LDS ops only; global h-stores stay in flight
    asm volatile("s_waitcnt lgkmcnt(0)\n\ts_barrier" ::: "memory");
  }
}

// K2: emission GEMM via MFMA: [65536 rows x 512] @ [512 x 48(35)] -> emis fp32.
__global__ __launch_bounds__(256) void emis_mfma(
    const unsigned short* __restrict__ hfu, const unsigned short* __restrict__ hbu,
    const float* __restrict__ clsw, const float* __restrict__ clsb,
    float* __restrict__ emis){
  __shared__ unsigned short wsm[48*520];                // bf16 [48][520], 512 used
  __shared__ __align__(16) unsigned short alds[128*40]; // [128][40] u16 (80B pitch)
  const int tid = threadIdx.x;
  const int lane = tid & 63;
  const int wid  = tid >> 6;
  for (int i=tid; i<6144; i+=256){
    int r = i >> 7, c4 = (i & 127)*4;
    uint2 pv;
    if (r < 35){
      float4 v = *(const float4*)(clsw + (size_t)r*512 + c4);
      pv.x = pk2(v.x, v.y); pv.y = pk2(v.z, v.w);
    } else { pv.x = 0u; pv.y = 0u; }
    *(uint2*)(wsm + r*520 + c4) = pv;
  }
  __syncthreads();
  floatx4 acc[2][3];
  #pragma unroll
  for (int mt=0;mt<2;++mt)
    #pragma unroll
    for (int nt=0;nt<3;++nt){ acc[mt][nt][0]=0;acc[mt][nt][1]=0;acc[mt][nt][2]=0;acc[mt][nt][3]=0; }

  const size_t row0 = (size_t)blockIdx.x*128;
  for (int ks=0; ks<16; ++ks){
    const unsigned short* hsrc = (ks<8) ? hfu : hbu;
    const int col = (ks&7)*32;
    __syncthreads();
    #pragma unroll
    for (int q=0;q<2;++q){
      int j = tid*2+q;           // 0..511
      int r = j>>2, c4 = j&3;
      uint4 v = *(const uint4*)(hsrc + (row0 + r)*256 + col + c4*8);
      *(uint4*)((char*)alds + r*80 + c4*16) = v;
    }
    __syncthreads();
    short8 bf[3];
    #pragma unroll
    for (int nt=0;nt<3;++nt){
      int rr = nt*16 + (lane&15);
      bf[nt] = *(const short8*)(wsm + rr*520 + ks*32 + (lane>>4)*8);
    }
    #pragma unroll
    for (int mt=0;mt<2;++mt){
      int r = (wid*2+mt)*16 + (lane&15);
      short8 af = *(const short8*)((char*)alds + r*80 + (lane>>4)*16);
      #pragma unroll
      for (int nt=0;nt<3;++nt)
        acc[mt][nt] = __builtin_amdgcn_mfma_f32_16x16x32_bf16(af, bf[nt], acc[mt][nt], 0,0,0);
    }
  }
  #pragma unroll
  for (int mt=0;mt<2;++mt){
    #pragma unroll
    for (int nt=0;nt<3;++nt){
      int tag = nt*16 + (lane&15);
      if (tag < NT){
        float bv = clsb[tag];
        #pragma unroll
        for (int j=0;j<4;++j){
          int m = (wid*2+mt)*16 + (lane>>4)*4 + j;
          emis[(row0 + m)*NT + tag] = acc[mt][nt][j] + bv;
        }
      }
    }
  }
}

// K3: gold score + CRF forward. 1 wave per batch, wave-synchronous.
__global__ void crf_kernel(const float* __restrict__ emis, const float* __restrict__ trans,
                           const int* __restrict__ tags, float* __restrict__ diff){
  const int b = blockIdx.x, l = threadIdx.x;   // 64 threads = 1 wave
  __shared__ float aLds[64];
  float gp = 0.f;
  for (int t=l; t<SL; t+=64){
    int tg = tags[b*SL+t];
    int pv = (t>0) ? tags[b*SL+t-1] : TSTART;
    gp += emis[((size_t)(b*SL)+t)*NT + tg] + trans[tg*NT+pv];
  }
  #pragma unroll
  for (int m=1;m<64;m<<=1) gp += __shfl_xor(gp, m);
  float Erow[NT];
  #pragma unroll
  for (int p=0;p<NT;++p) Erow[p] = (l<NT) ? __expf(trans[l*NT+p]) : 0.f;
  aLds[l] = (l==TSTART) ? 1.f : 0.f;
  float logZ = 0.f;
  const float* ep = emis + (size_t)b*SL*NT;
  float epre = (l<NT) ? ep[l] : 0.f;
  for (int t=0; t<SL; ++t){
    float ev = __expf(epre);
    int tn = (t+1 < SL) ? (t+1) : (SL-1);
    epre = (l<NT) ? ep[(size_t)tn*NT + l] : 0.f;
    float s0=0.f, s1=0.f, s2=0.f, s3=0.f;
    #pragma unroll
    for (int p=0;p<32;p+=4){
      s0 += Erow[p  ]*aLds[p  ];
      s1 += Erow[p+1]*aLds[p+1];
      s2 += Erow[p+2]*aLds[p+2];
      s3 += Erow[p+3]*aLds[p+3];
    }
    s0 += Erow[32]*aLds[32];
    s1 += Erow[33]*aLds[33];
    s2 += Erow[34]*aLds[34];
    float v = ((s0+s1)+(s2+s3)) * ev;      // lanes >= NT: 0
    float tot = v;
    #pragma unroll
    for (int m=1;m<64;m<<=1) tot += __shfl_xor(tot, m);
    logZ += __logf(tot);
    aLds[l] = v * __builtin_amdgcn_rcpf(tot);   // wave-order LDS
  }
  if (l == 0) diff[b] = logZ - gp;
}

// K4: loss = mean(diff)
__global__ void final_kernel(const float* __restrict__ diff, float* __restrict__ out){
  int l = threadIdx.x;
  float v = diff[l];
  #pragma unroll
  for (int m=1;m<64;m<<=1) v += __shfl_xor(v, m);
  if (l == 0) out[0] = v * (1.f/64.f);
}

extern "C" void kernel_launch(void* const* d_in, const int* in_sizes, int n_in,
                              void* d_out, int out_size, void* d_ws, size_t ws_size,
                              hipStream_t stream){
  const int*   data = (const int*)d_in[0];
  const int*   tags = (const int*)d_in[2];
  const float* emb  = (const float*)d_in[3];
  const float* wihf = (const float*)d_in[4];
  const float* whhf = (const float*)d_in[5];
  const float* bihf = (const float*)d_in[6];
  const float* bhhf = (const float*)d_in[7];
  const float* wihb = (const float*)d_in[8];
  const float* whhb = (const float*)d_in[9];
  const float* bihb = (const float*)d_in[10];
  const float* bhhb = (const float*)d_in[11];
  const float* clsw = (const float*)d_in[12];
  const float* clsb = (const float*)d_in[13];
  const float* trans= (const float*)d_in[14];

  char* ws = (char*)d_ws;
  unsigned short* hf = (unsigned short*)(ws);            // 33,554,432 B
  unsigned short* hb = (unsigned short*)(ws + 33554432); // 33,554,432 B
  uint*  xf8  = (uint*)(ws + 67108864);                  //  8,388,608 B (lstm-only)
  float* emis = (float*)(ws + 67108864);                 //  9,175,040 B (overlays xf8 post-lstm)
  float* diff = (float*)(ws + 76283904);                 //        256 B
  float* out  = (float*)d_out;

  xgather8<<<dim3(8192), dim3(256), 0, stream>>>(data, emb, xf8);
  lstm_block<<<dim3(8), dim3(512), 0, stream>>>(
      xf8, wihf, whhf, bihf, bhhf, wihb, whhb, bihb, bhhb, hf, hb);
  emis_mfma<<<dim3(512), dim3(256), 0, stream>>>(hf, hb, clsw, clsb, emis);
  crf_kernel<<<dim3(64), dim3(64), 0, stream>>>(emis, trans, tags, diff);
  final_kernel<<<dim3(1), dim3(64), 0, stream>>>(diff, out);
}

// Round 8
// 2626.387 us; speedup vs baseline: 13.9575x; 1.3168x over previous
//
#include <hip/hip_runtime.h>
#include <hip/hip_bf16.h>
#include <cstdint>

#define NB 64      // batch
#define SL 1024    // seq len
#define ED 128     // embed
#define HD 256     // hidden
#define NT 35      // tags
#define TSTART 33

typedef unsigned int uint;
typedef __attribute__((ext_vector_type(8))) short short8;
typedef __attribute__((ext_vector_type(4))) float floatx4;

__device__ __forceinline__ float fsig(float x){
  return __builtin_amdgcn_rcpf(1.f + __expf(-x));
}
__device__ __forceinline__ float ftanh(float x){
  float ax = fabsf(x);
  float e  = __expf(2.f*ax);
  float r  = 1.f - 2.f*__builtin_amdgcn_rcpf(e+1.f);
  return copysignf(r, x);
}
__device__ __forceinline__ unsigned short f2bf(float f){
  __hip_bfloat16 b = __float2bfloat16(f);
  return __builtin_bit_cast(unsigned short, b);
}
__device__ __forceinline__ float bf2f(unsigned short v){
  return __uint_as_float(((uint)v)<<16);
}
__device__ __forceinline__ uint pk2(float a, float b){
  return (uint)f2bf(a) | ((uint)f2bf(b)<<16);
}

// ---- fp8 e4m3 (OCP) encode: builtin if available, manual fallback ----
__device__ __forceinline__ uint enc_e4m3(float f){
  uint s = (__float_as_uint(f) >> 24) & 0x80u;
  float a = fabsf(f);
  if (a >= 448.f) return s | 0x7Eu;
  if (a < 0.0009765625f) return s;
  int e; float m = frexpf(a, &e);
  int E = e + 6;
  if (E >= 1){
    uint mb = (uint)rintf(m*16.f);
    if (mb >= 16u){ E += 1; mb = 8u; }
    if (E > 15) return s | 0x7Eu;
    return s | ((uint)E<<3) | (mb - 8u);
  } else {
    uint mb = (uint)rintf(a*512.f);
    if (mb > 7u) return s | 0x08u;
    return s | mb;
  }
}
__device__ __forceinline__ uint cvt2(float a, float b){
#if __has_builtin(__builtin_amdgcn_cvt_pk_fp8_f32)
  return ((uint)__builtin_amdgcn_cvt_pk_fp8_f32(a, b, 0, false)) & 0xFFFFu;
#else
  return enc_e4m3(a) | (enc_e4m3(b)<<8);
#endif
}
// exact manual e4m3fn decode (inverts our encoder bit-for-bit)
__device__ __forceinline__ float dec8(uint b){
  uint e = (b>>3)&15u, m = b&7u;
  float v;
  if (e) v = __uint_as_float(((e+120u)<<23)|(m<<20));
  else   v = (float)m * 0.001953125f;   // m * 2^-9
  return (b & 0x80u) ? -v : v;
}

// K0: xg GEMM — xg[dir][b][tl][g] = fp8( 16*( W_ih x(b,t) + b_ih + b_hh ) ).
// Tile: 128 rows(b,t) x 128 gates, K=128 (bf16 MFMA). Grid (rows/128, 8, 2dir).
__global__ __launch_bounds__(256) void xg_gemm(
    const int* __restrict__ data, const float* __restrict__ emb,
    const float* __restrict__ wihf, const float* __restrict__ wihb,
    const float* __restrict__ bihf, const float* __restrict__ bhhf,
    const float* __restrict__ bihb, const float* __restrict__ bhhb,
    unsigned char* __restrict__ xg, int t0f, int t0b, int S, int logS){
  const int dir = blockIdx.z, gtl = blockIdx.y, rt = blockIdx.x;
  const int tid = threadIdx.x, lane = tid&63, wid = tid>>6;
  const int n15 = lane&15, kgr = lane>>4;
  __shared__ int tok[128];
  __shared__ __align__(16) unsigned short Asm2[128*136];
  __shared__ __align__(16) unsigned short Bsm[128*136];
  __shared__ unsigned char obuf[128*132];
  const float* Wih = dir ? wihb : wihf;
  const float* Bi  = dir ? bihb : bihf;
  const float* Bh  = dir ? bhhb : bhhf;
  const int t0 = dir ? t0b : t0f;
  if (tid < 128){
    int r = rt*128 + tid;
    int b = r >> logS, tl = r & (S-1);
    tok[tid] = data[b*SL + t0 + tl];
  }
  __syncthreads();
  {
    int row = tid >> 1, c0 = (tid&1)*64;
    const float* sa = emb + (size_t)tok[row]*ED + c0;
    const float* sb = Wih + (size_t)(gtl*128 + row)*ED + c0;
    #pragma unroll
    for (int c=0; c<64; c+=8){
      float4 f0 = *(const float4*)(sa+c), f1 = *(const float4*)(sa+c+4);
      uint4 pv; pv.x = pk2(f0.x,f0.y); pv.y = pk2(f0.z,f0.w);
      pv.z = pk2(f1.x,f1.y); pv.w = pk2(f1.z,f1.w);
      *(uint4*)(Asm2 + row*136 + c0 + c) = pv;
      float4 g0 = *(const float4*)(sb+c), g1 = *(const float4*)(sb+c+4);
      uint4 qv; qv.x = pk2(g0.x,g0.y); qv.y = pk2(g0.z,g0.w);
      qv.z = pk2(g1.x,g1.y); qv.w = pk2(g1.z,g1.w);
      *(uint4*)(Bsm + row*136 + c0 + c) = qv;
    }
  }
  __syncthreads();
  floatx4 acc[2][8];
  #pragma unroll
  for (int mt=0;mt<2;++mt)
    #pragma unroll
    for (int nt=0;nt<8;++nt){ acc[mt][nt][0]=0;acc[mt][nt][1]=0;acc[mt][nt][2]=0;acc[mt][nt][3]=0; }
  #pragma unroll
  for (int kt=0; kt<4; ++kt){
    short8 af[2];
    #pragma unroll
    for (int mt=0; mt<2; ++mt)
      af[mt] = *(const short8*)(Asm2 + ((wid*2+mt)*16 + n15)*136 + kt*32 + kgr*8);
    #pragma unroll
    for (int nt=0; nt<8; ++nt){
      short8 bfv = *(const short8*)(Bsm + (nt*16 + n15)*136 + kt*32 + kgr*8);
      #pragma unroll
      for (int mt=0; mt<2; ++mt)
        acc[mt][nt] = __builtin_amdgcn_mfma_f32_16x16x32_bf16(af[mt], bfv, acc[mt][nt], 0,0,0);
    }
  }
  float b16[8];
  #pragma unroll
  for (int nt=0; nt<8; ++nt){
    int g = gtl*128 + nt*16 + n15;
    b16[nt] = 16.f*(Bi[g] + Bh[g]);
  }
  #pragma unroll
  for (int mt=0;mt<2;++mt)
    #pragma unroll
    for (int nt=0;nt<8;++nt)
      #pragma unroll
      for (int j=0;j<4;++j){
        int row = (wid*2+mt)*16 + kgr*4 + j;
        float v = 16.f*acc[mt][nt][j] + b16[nt];
        obuf[row*132 + nt*16 + n15] = (unsigned char)(cvt2(v, 0.f) & 0xFFu);
      }
  __syncthreads();
  {
    int r2 = tid>>1, c0 = (tid&1)*64;
    size_t base = ((size_t)dir*64*S + (size_t)rt*128 + r2)*1024 + gtl*128 + c0;
    #pragma unroll
    for (int i=0;i<4;++i){
      uint4 v;
      v.x = *(const uint*)(obuf + r2*132 + c0 + i*16 + 0);
      v.y = *(const uint*)(obuf + r2*132 + c0 + i*16 + 4);
      v.z = *(const uint*)(obuf + r2*132 + c0 + i*16 + 8);
      v.w = *(const uint*)(obuf + r2*132 + c0 + i*16 + 12);
      *(uint4*)(xg + base + i*16) = v;
    }
  }
}

// K1: recurrence-only BiLSTM. Grid (32 pairs, 2 dir) x 512 thr (8 waves).
// W_hh (256x1024, fp8 16W) register/AGPR-resident: wave w owns gate-rows
// [w*128, w*128+128). Per step: 64 MFMA/wave (K=256) -> gate bounce (8KB LDS)
// -> each thread computes exactly ONE h (batch tid>>8, unit tid&255):
// gate = (acc + xg)/16, c/h update, h -> fp8 A-tile + bf16 global.
// 2 raw barriers/step (lgkmcnt only; global h-stores stay in flight).
__global__ __launch_bounds__(512, 2) void lstm_rec(
    const unsigned char* __restrict__ xg,
    const float* __restrict__ whhf, const float* __restrict__ whhb,
    unsigned short* __restrict__ hf, unsigned short* __restrict__ hb,
    float* __restrict__ cbuf,
    int t0f, int t0b, int S, int first){
  const int tid = threadIdx.x, lane = tid&63, w = tid>>6;
  const int n15 = lane&15, kg = lane>>4;
  const int grp = blockIdx.x, dir = blockIdx.y;
  const int b0 = grp*2;
  __shared__ __align__(16) unsigned char Atile[2][544];
  __shared__ __align__(16) unsigned char xgl[2][2048];
  __shared__ float bounce[2048];
  const float* Whh = dir ? whhb : whhf;
  unsigned short* hout = dir ? hb : hf;
  const int t0 = dir ? t0b : t0f;

  // one-time: W_hh fragments (fp8 of 16W), 64 longs -> AGPR/VGPR
  long long whhR[8][8];
  #pragma unroll
  for (int q=0;q<8;++q){
    int R = w*128 + q*16 + n15;
    #pragma unroll
    for (int kt=0;kt<8;++kt){
      const float* src = Whh + (size_t)R*HD + kt*32 + kg*8;
      float4 f0 = *(const float4*)src, f1 = *(const float4*)(src+4);
      uint2 p;
      p.x = cvt2(16.f*f0.x,16.f*f0.y) | (cvt2(16.f*f0.z,16.f*f0.w)<<16);
      p.y = cvt2(16.f*f1.x,16.f*f1.y) | (cvt2(16.f*f1.z,16.f*f1.w)<<16);
      whhR[q][kt] = __builtin_bit_cast(long long, p);
    }
  }

  const int bb = tid >> 8, uu = tid & 255;
  float cst = 0.f;
  // prologue: h(prev)/c(prev) for this chunk; xg(first t) into xgl[0]
  {
    float hprev = 0.f;
    if (!first){
      int tprev = dir ? (t0b + S) : (t0f - 1);
      hprev = bf2f(hout[((size_t)(b0+bb)*SL + tprev)*256 + uu]);
      cst = cbuf[(size_t)(dir*64 + b0 + bb)*256 + uu];
    }
    Atile[0][bb*264 + uu] = (unsigned char)(cvt2(hprev,0.f)&0xFFu);
    int tl0 = dir ? (S-1) : 0;
    uint xv = *(const uint*)(xg + ((size_t)(dir*64 + b0 + bb)*S + tl0)*1024 + uu*4);
    *(uint*)(&xgl[0][bb*1024 + uu*4]) = xv;
  }
  __syncthreads();

  for (int i=0;i<S;++i){
    const int cur = i&1, nxt = cur^1;
    const int tl = dir ? (S-1-i) : i;
    const int t  = t0 + tl;
    // prefetch next xg (latency hides under MFMA + bounce)
    uint xv = 0u;
    if (i+1 < S){
      int tln = dir ? (tl-1) : (tl+1);
      xv = *(const uint*)(xg + ((size_t)(dir*64 + b0 + bb)*S + tln)*1024 + uu*4);
    }
    // MFMA: gates = 16*(W_hh h)
    floatx4 acc[8];
    #pragma unroll
    for (int q=0;q<8;++q){ acc[q][0]=0;acc[q][1]=0;acc[q][2]=0;acc[q][3]=0; }
    #pragma unroll
    for (int kt=0;kt<8;++kt){
      long long la = *(const long long*)(&Atile[cur][(n15&1)*264 + kt*32 + kg*8]);
      #pragma unroll
      for (int q=0;q<8;++q)
        acc[q] = __builtin_amdgcn_mfma_f32_16x16x32_fp8_fp8(la, whhR[q][kt], acc[q], 0,0,0);
    }
    // bounce: D rows m=0,1 (valid batches) live in kg==0 lanes, regs j=0,1
    if (kg == 0){
      #pragma unroll
      for (int q=0;q<8;++q){
        int R = w*128 + q*16 + n15;
        bounce[R]        = acc[q][0];
        bounce[1024 + R] = acc[q][1];
      }
    }
    asm volatile("s_waitcnt lgkmcnt(0)\n\ts_barrier" ::: "memory");
    // h-compute: one h per thread
    float g4[4];
    #pragma unroll
    for (int gt=0;gt<4;++gt){
      float gs = bounce[bb*1024 + gt*256 + uu];
      float xd = dec8(xgl[cur][bb*1024 + gt*256 + uu]);
      g4[gt] = (gs + xd)*0.0625f;
    }
    float cnew = fsig(g4[1])*cst + fsig(g4[0])*ftanh(g4[2]);
    cst = cnew;
    float h = fsig(g4[3])*ftanh(cnew);
    Atile[nxt][bb*264+uu] = (unsigned char)(cvt2(h,0.f)&0xFFu);
    hout[((size_t)(b0+bb)*SL + t)*256 + uu] = f2bf(h);
    if (i+1 < S) *(uint*)(&xgl[nxt][bb*1024 + uu*4]) = xv;
    asm volatile("s_waitcnt lgkmcnt(0)\n\ts_barrier" ::: "memory");
  }
  cbuf[(size_t)(dir*64 + b0 + bb)*256 + uu] = cst;
}

// K2: emission GEMM via MFMA: [65536 rows x 512] @ [512 x 48(35)] -> emis fp32.
__global__ __launch_bounds__(256) void emis_mfma(
    const unsigned short* __restrict__ hfu, const unsigned short* __restrict__ hbu,
    const float* __restrict__ clsw, const float* __restrict__ clsb,
    float* __restrict__ emis){
  __shared__ unsigned short wsm[48*520];
  __shared__ __align__(16) unsigned short alds[128*40];
  const int tid = threadIdx.x;
  const int lane = tid & 63;
  const int wid  = tid >> 6;
  for (int i=tid; i<6144; i+=256){
    int r = i >> 7, c4 = (i & 127)*4;
    uint2 pv;
    if (r < 35){
      float4 v = *(const float4*)(clsw + (size_t)r*512 + c4);
      pv.x = pk2(v.x, v.y); pv.y = pk2(v.z, v.w);
    } else { pv.x = 0u; pv.y = 0u; }
    *(uint2*)(wsm + r*520 + c4) = pv;
  }
  __syncthreads();
  floatx4 acc[2][3];
  #pragma unroll
  for (int mt=0;mt<2;++mt)
    #pragma unroll
    for (int nt=0;nt<3;++nt){ acc[mt][nt][0]=0;acc[mt][nt][1]=0;acc[mt][nt][2]=0;acc[mt][nt][3]=0; }

  const size_t row0 = (size_t)blockIdx.x*128;
  for (int ks=0; ks<16; ++ks){
    const unsigned short* hsrc = (ks<8) ? hfu : hbu;
    const int col = (ks&7)*32;
    __syncthreads();
    #pragma unroll
    for (int q=0;q<2;++q){
      int j = tid*2+q;
      int r = j>>2, c4 = j&3;
      uint4 v = *(const uint4*)(hsrc + (row0 + r)*256 + col + c4*8);
      *(uint4*)((char*)alds + r*80 + c4*16) = v;
    }
    __syncthreads();
    short8 bfv[3];
    #pragma unroll
    for (int nt=0;nt<3;++nt){
      int rr = nt*16 + (lane&15);
      bfv[nt] = *(const short8*)(wsm + rr*520 + ks*32 + (lane>>4)*8);
    }
    #pragma unroll
    for (int mt=0;mt<2;++mt){
      int r = (wid*2+mt)*16 + (lane&15);
      short8 af = *(const short8*)((char*)alds + r*80 + (lane>>4)*16);
      #pragma unroll
      for (int nt=0;nt<3;++nt)
        acc[mt][nt] = __builtin_amdgcn_mfma_f32_16x16x32_bf16(af, bfv[nt], acc[mt][nt], 0,0,0);
    }
  }
  #pragma unroll
  for (int mt=0;mt<2;++mt){
    #pragma unroll
    for (int nt=0;nt<3;++nt){
      int tag = nt*16 + (lane&15);
      if (tag < NT){
        float bv = clsb[tag];
        #pragma unroll
        for (int j=0;j<4;++j){
          int m = (wid*2+mt)*16 + (lane>>4)*4 + j;
          emis[(row0 + m)*NT + tag] = acc[mt][nt][j] + bv;
        }
      }
    }
  }
}

// K3: gold score + CRF forward. 1 wave per batch, wave-synchronous.
__global__ void crf_kernel(const float* __restrict__ emis, const float* __restrict__ trans,
                           const int* __restrict__ tags, float* __restrict__ diff){
  const int b = blockIdx.x, l = threadIdx.x;
  __shared__ float aLds[64];
  float gp = 0.f;
  for (int t=l; t<SL; t+=64){
    int tg = tags[b*SL+t];
    int pv = (t>0) ? tags[b*SL+t-1] : TSTART;
    gp += emis[((size_t)(b*SL)+t)*NT + tg] + trans[tg*NT+pv];
  }
  #pragma unroll
  for (int m=1;m<64;m<<=1) gp += __shfl_xor(gp, m);
  float Erow[NT];
  #pragma unroll
  for (int p=0;p<NT;++p) Erow[p] = (l<NT) ? __expf(trans[l*NT+p]) : 0.f;
  aLds[l] = (l==TSTART) ? 1.f : 0.f;
  float logZ = 0.f;
  const float* ep = emis + (size_t)b*SL*NT;
  float epre = (l<NT) ? ep[l] : 0.f;
  for (int t=0; t<SL; ++t){
    float ev = __expf(epre);
    int tn = (t+1 < SL) ? (t+1) : (SL-1);
    epre = (l<NT) ? ep[(size_t)tn*NT + l] : 0.f;
    float s0=0.f, s1=0.f, s2=0.f, s3=0.f;
    #pragma unroll
    for (int p=0;p<32;p+=4){
      s0 += Erow[p  ]*aLds[p  ];
      s1 += Erow[p+1]*aLds[p+1];
      s2 += Erow[p+2]*aLds[p+2];
      s3 += Erow[p+3]*aLds[p+3];
    }
    s0 += Erow[32]*aLds[32];
    s1 += Erow[33]*aLds[33];
    s2 += Erow[34]*aLds[34];
    float v = ((s0+s1)+(s2+s3)) * ev;
    float tot = v;
    #pragma unroll
    for (int m=1;m<64;m<<=1) tot += __shfl_xor(tot, m);
    logZ += __logf(tot);
    aLds[l] = v * __builtin_amdgcn_rcpf(tot);
  }
  if (l == 0) diff[b] = logZ - gp;
}

// K4: loss = mean(diff)
__global__ void final_kernel(const float* __restrict__ diff, float* __restrict__ out){
  int l = threadIdx.x;
  float v = diff[l];
  #pragma unroll
  for (int m=1;m<64;m<<=1) v += __shfl_xor(v, m);
  if (l == 0) out[0] = v * (1.f/64.f);
}

extern "C" void kernel_launch(void* const* d_in, const int* in_sizes, int n_in,
                              void* d_out, int out_size, void* d_ws, size_t ws_size,
                              hipStream_t stream){
  const int*   data = (const int*)d_in[0];
  const int*   tags = (const int*)d_in[2];
  const float* emb  = (const float*)d_in[3];
  const float* wihf = (const float*)d_in[4];
  const float* whhf = (const float*)d_in[5];
  const float* bihf = (const float*)d_in[6];
  const float* bhhf = (const float*)d_in[7];
  const float* wihb = (const float*)d_in[8];
  const float* whhb = (const float*)d_in[9];
  const float* bihb = (const float*)d_in[10];
  const float* bhhb = (const float*)d_in[11];
  const float* clsw = (const float*)d_in[12];
  const float* clsb = (const float*)d_in[13];
  const float* trans= (const float*)d_in[14];

  char* ws = (char*)d_ws;
  unsigned short* hf = (unsigned short*)(ws);              // 33,554,432 B
  unsigned short* hb = (unsigned short*)(ws + 33554432);   // 33,554,432 B
  float* cbuf = (float*)(ws + 67108864);                   //     65,536 B
  unsigned char* xgp = (unsigned char*)(ws + 67174400);    // 2*64*S*1024 B
  float* emis = (float*)(ws + 67174400);                   // overlays xg post-lstm

  // choose time-chunking from ws_size; worst case S=128 needs 83.95 MB
  // (below the 84.15 MB footprint proven in earlier rounds).
  int S = 128;
  for (int cand = 1024; cand >= 128; cand >>= 1){
    size_t need = 67174400ull + (size_t)2*64*cand*1024 + 4096ull;
    if (need <= ws_size){ S = cand; break; }
  }
  const int NC = SL / S;
  const int logS = 31 - __builtin_clz((unsigned)S);
  float* diff = (float*)(ws + 67174400 + (size_t)2*64*S*1024);
  float* out  = (float*)d_out;

  for (int k=0; k<NC; ++k){
    int t0f = k*S, t0b = SL - (k+1)*S;
    xg_gemm<<<dim3(S*64/128, 8, 2), dim3(256), 0, stream>>>(
        data, emb, wihf, wihb, bihf, bhhf, bihb, bhhb, xgp, t0f, t0b, S, logS);
    lstm_rec<<<dim3(32, 2), dim3(512), 0, stream>>>(
        xgp, whhf, whhb, hf, hb, cbuf, t0f, t0b, S, (k==0) ? 1 : 0);
  }
  emis_mfma<<<dim3(512), dim3(256), 0, stream>>>(hf, hb, clsw, clsb, emis);
  crf_kernel<<<dim3(64), dim3(64), 0, stream>>>(emis, trans, tags, diff);
  final_kernel<<<dim3(1), dim3(64), 0, stream>>>(diff, out);
}

// Round 9
// 1983.138 us; speedup vs baseline: 18.4848x; 1.3244x over previous
//
#include <hip/hip_runtime.h>
#include <hip/hip_bf16.h>
#include <cstdint>

#define NB 64      // batch
#define SL 1024    // seq len
#define ED 128     // embed
#define HD 256     // hidden
#define NT 35      // tags
#define TSTART 33

typedef unsigned int uint;
typedef __attribute__((ext_vector_type(8))) short short8;
typedef __attribute__((ext_vector_type(4))) float floatx4;
typedef __attribute__((ext_vector_type(4))) int intx4;

__device__ __forceinline__ float fsig(float x){
  return __builtin_amdgcn_rcpf(1.f + __expf(-x));
}
__device__ __forceinline__ float ftanh(float x){
  float ax = fabsf(x);
  float e  = __expf(2.f*ax);
  float r  = 1.f - 2.f*__builtin_amdgcn_rcpf(e+1.f);
  return copysignf(r, x);
}
__device__ __forceinline__ unsigned short f2bf(float f){
  __hip_bfloat16 b = __float2bfloat16(f);
  return __builtin_bit_cast(unsigned short, b);
}
__device__ __forceinline__ float bf2f(unsigned short v){
  return __uint_as_float(((uint)v)<<16);
}
__device__ __forceinline__ uint pk2(float a, float b){
  return (uint)f2bf(a) | ((uint)f2bf(b)<<16);
}

// ---- fp8 e4m3 (OCP) encode: builtin if available, manual fallback ----
__device__ __forceinline__ uint enc_e4m3(float f){
  uint s = (__float_as_uint(f) >> 24) & 0x80u;
  float a = fabsf(f);
  if (a >= 448.f) return s | 0x7Eu;
  if (a < 0.0009765625f) return s;
  int e; float m = frexpf(a, &e);
  int E = e + 6;
  if (E >= 1){
    uint mb = (uint)rintf(m*16.f);
    if (mb >= 16u){ E += 1; mb = 8u; }
    if (E > 15) return s | 0x7Eu;
    return s | ((uint)E<<3) | (mb - 8u);
  } else {
    uint mb = (uint)rintf(a*512.f);
    if (mb > 7u) return s | 0x08u;
    return s | mb;
  }
}
__device__ __forceinline__ uint cvt2(float a, float b){
#if __has_builtin(__builtin_amdgcn_cvt_pk_fp8_f32)
  return ((uint)__builtin_amdgcn_cvt_pk_fp8_f32(a, b, 0, false)) & 0xFFFFu;
#else
  return enc_e4m3(a) | (enc_e4m3(b)<<8);
#endif
}
// branchless fp8 e4m3fn decode: as_float((b&0x7f)<<20) * 2^120, sign OR'd.
// (fp8 denorms may flush to 0 under FTZ: |err| <= 7*2^-9 pre-scale — negligible.)
__device__ __forceinline__ float dec8f(uint b){
  float m = __uint_as_float((b & 0x7Fu) << 20) * 0x1p120f;
  return __uint_as_float(__float_as_uint(m) | ((b & 0x80u) << 24));
}

// K0: xg GEMM — xg[dir][b][tl][g] = fp8( 16*( W_ih x(b,t) + b_ih + b_hh ) ).
// Tile: 128 rows(b,t) x 128 gates, K=128 (bf16 MFMA). Grid (rows/128, 8, 2dir).
__global__ __launch_bounds__(256) void xg_gemm(
    const int* __restrict__ data, const float* __restrict__ emb,
    const float* __restrict__ wihf, const float* __restrict__ wihb,
    const float* __restrict__ bihf, const float* __restrict__ bhhf,
    const float* __restrict__ bihb, const float* __restrict__ bhhb,
    unsigned char* __restrict__ xg, int t0f, int t0b, int S, int logS){
  const int dir = blockIdx.z, gtl = blockIdx.y, rt = blockIdx.x;
  const int tid = threadIdx.x, lane = tid&63, wid = tid>>6;
  const int n15 = lane&15, kgr = lane>>4;
  __shared__ int tok[128];
  __shared__ __align__(16) unsigned short Asm2[128*136];
  __shared__ __align__(16) unsigned short Bsm[128*136];
  __shared__ unsigned char obuf[128*132];
  const float* Wih = dir ? wihb : wihf;
  const float* Bi  = dir ? bihb : bihf;
  const float* Bh  = dir ? bhhb : bhhf;
  const int t0 = dir ? t0b : t0f;
  if (tid < 128){
    int r = rt*128 + tid;
    int b = r >> logS, tl = r & (S-1);
    tok[tid] = data[b*SL + t0 + tl];
  }
  __syncthreads();
  {
    int row = tid >> 1, c0 = (tid&1)*64;
    const float* sa = emb + (size_t)tok[row]*ED + c0;
    const float* sb = Wih + (size_t)(gtl*128 + row)*ED + c0;
    #pragma unroll
    for (int c=0; c<64; c+=8){
      float4 f0 = *(const float4*)(sa+c), f1 = *(const float4*)(sa+c+4);
      uint4 pv; pv.x = pk2(f0.x,f0.y); pv.y = pk2(f0.z,f0.w);
      pv.z = pk2(f1.x,f1.y); pv.w = pk2(f1.z,f1.w);
      *(uint4*)(Asm2 + row*136 + c0 + c) = pv;
      float4 g0 = *(const float4*)(sb+c), g1 = *(const float4*)(sb+c+4);
      uint4 qv; qv.x = pk2(g0.x,g0.y); qv.y = pk2(g0.z,g0.w);
      qv.z = pk2(g1.x,g1.y); qv.w = pk2(g1.z,g1.w);
      *(uint4*)(Bsm + row*136 + c0 + c) = qv;
    }
  }
  __syncthreads();
  floatx4 acc[2][8];
  #pragma unroll
  for (int mt=0;mt<2;++mt)
    #pragma unroll
    for (int nt=0;nt<8;++nt){ acc[mt][nt][0]=0;acc[mt][nt][1]=0;acc[mt][nt][2]=0;acc[mt][nt][3]=0; }
  #pragma unroll
  for (int kt=0; kt<4; ++kt){
    short8 af[2];
    #pragma unroll
    for (int mt=0; mt<2; ++mt)
      af[mt] = *(const short8*)(Asm2 + ((wid*2+mt)*16 + n15)*136 + kt*32 + kgr*8);
    #pragma unroll
    for (int nt=0; nt<8; ++nt){
      short8 bfv = *(const short8*)(Bsm + (nt*16 + n15)*136 + kt*32 + kgr*8);
      #pragma unroll
      for (int mt=0; mt<2; ++mt)
        acc[mt][nt] = __builtin_amdgcn_mfma_f32_16x16x32_bf16(af[mt], bfv, acc[mt][nt], 0,0,0);
    }
  }
  float b16[8];
  #pragma unroll
  for (int nt=0; nt<8; ++nt){
    int g = gtl*128 + nt*16 + n15;
    b16[nt] = 16.f*(Bi[g] + Bh[g]);
  }
  #pragma unroll
  for (int mt=0;mt<2;++mt)
    #pragma unroll
    for (int nt=0;nt<8;++nt)
      #pragma unroll
      for (int j=0;j<4;++j){
        int row = (wid*2+mt)*16 + kgr*4 + j;
        float v = 16.f*acc[mt][nt][j] + b16[nt];
        obuf[row*132 + nt*16 + n15] = (unsigned char)(cvt2(v, 0.f) & 0xFFu);
      }
  __syncthreads();
  {
    int r2 = tid>>1, c0 = (tid&1)*64;
    size_t base = ((size_t)dir*64*S + (size_t)rt*128 + r2)*1024 + gtl*128 + c0;
    #pragma unroll
    for (int i=0;i<4;++i){
      uint4 v;
      v.x = *(const uint*)(obuf + r2*132 + c0 + i*16 + 0);
      v.y = *(const uint*)(obuf + r2*132 + c0 + i*16 + 4);
      v.z = *(const uint*)(obuf + r2*132 + c0 + i*16 + 8);
      v.w = *(const uint*)(obuf + r2*132 + c0 + i*16 + 12);
      *(uint4*)(xg + base + i*16) = v;
    }
  }
}

// K1: recurrence-only BiLSTM, i8 MFMA (16x16x64, K=64: HALF the matrix-pipe
// cycles of the fp8 K=32 version — the r8 counters showed 47% per-CU MfmaUtil,
// i.e. MFMA-pipe-bound). W_hh quantized once: wq = rint(W*2032) (|W|<=1/16 ->
// |wq|<=127); h quantized per step: hq = rint(h*127); gates recovered exactly:
// g = acc/(127*2032) + xg/16. Structure identical to r8 (bounce + 2 raw
// barriers, xg fp8 staging, chunked S).
__global__ __launch_bounds__(512, 2) void lstm_rec(
    const unsigned char* __restrict__ xg,
    const float* __restrict__ whhf, const float* __restrict__ whhb,
    unsigned short* __restrict__ hf, unsigned short* __restrict__ hb,
    float* __restrict__ cbuf,
    int t0f, int t0b, int S, int first){
  const int tid = threadIdx.x, lane = tid&63, w = tid>>6;
  const int n15 = lane&15, kg = lane>>4;
  const int grp = blockIdx.x, dir = blockIdx.y;
  const int b0 = grp*2;
  __shared__ __align__(16) unsigned char Atile[2][544];   // pitch 272 (16-aligned)
  __shared__ __align__(16) unsigned char xgl[2][2048];
  __shared__ float bounce[2048];
  const float* Whh = dir ? whhb : whhf;
  unsigned short* hout = dir ? hb : hf;
  const int t0 = dir ? t0b : t0f;

  // one-time: W_hh i8 fragments (rint(W*2032)), 8 tiles x 4 kt x 16B = 128 regs
  intx4 whhQ[8][4];
  #pragma unroll
  for (int q=0;q<8;++q){
    int R = w*128 + q*16 + n15;
    #pragma unroll
    for (int kt=0;kt<4;++kt){
      int dw[4];
      #pragma unroll
      for (int d=0;d<4;++d){
        uint pv = 0u;
        #pragma unroll
        for (int e=0;e<4;++e){
          float wv = Whh[(size_t)R*HD + kt*64 + kg*16 + d*4 + e];
          int iv = (int)rintf(wv*2032.f);
          iv = iv > 127 ? 127 : (iv < -127 ? -127 : iv);
          pv |= ((uint)iv & 0xFFu) << (8*e);
        }
        dw[d] = (int)pv;
      }
      intx4 v; v[0]=dw[0]; v[1]=dw[1]; v[2]=dw[2]; v[3]=dw[3];
      whhQ[q][kt] = v;
    }
  }

  const int bb = tid >> 8, uu = tid & 255;
  float cst = 0.f;
  // prologue: h(prev)/c(prev); xg(first t) into xgl[0]
  {
    float hprev = 0.f;
    if (!first){
      int tprev = dir ? (t0b + S) : (t0f - 1);
      hprev = bf2f(hout[((size_t)(b0+bb)*SL + tprev)*256 + uu]);
      cst = cbuf[(size_t)(dir*64 + b0 + bb)*256 + uu];
    }
    int hq = (int)rintf(hprev*127.f);
    Atile[0][bb*272 + uu] = (unsigned char)(hq & 0xFF);
    int tl0 = dir ? (S-1) : 0;
    uint xv = *(const uint*)(xg + ((size_t)(dir*64 + b0 + bb)*S + tl0)*1024 + uu*4);
    *(uint*)(&xgl[0][bb*1024 + uu*4]) = xv;
  }
  __syncthreads();

  const float invQ = 1.f/258064.f;   // 1/(127*2032)
  for (int i=0;i<S;++i){
    const int cur = i&1, nxt = cur^1;
    const int tl = dir ? (S-1-i) : i;
    const int t  = t0 + tl;
    // prefetch next xg (latency hides under MFMA + bounce)
    uint xv = 0u;
    if (i+1 < S){
      int tln = dir ? (tl-1) : (tl+1);
      xv = *(const uint*)(xg + ((size_t)(dir*64 + b0 + bb)*S + tln)*1024 + uu*4);
    }
    // MFMA: acc = 127*2032*(W_hh h), exact i32
    intx4 acc[8];
    #pragma unroll
    for (int q=0;q<8;++q){ acc[q][0]=0;acc[q][1]=0;acc[q][2]=0;acc[q][3]=0; }
    uint4 la[4];
    #pragma unroll
    for (int kt=0;kt<4;++kt)
      la[kt] = *(const uint4*)(&Atile[cur][(n15&1)*272 + kt*64 + kg*16]);
    #pragma unroll
    for (int kt=0;kt<4;++kt){
      intx4 av = __builtin_bit_cast(intx4, la[kt]);
      #pragma unroll
      for (int q=0;q<8;++q)
        acc[q] = __builtin_amdgcn_mfma_i32_16x16x64_i8(av, whhQ[q][kt], acc[q], 0,0,0);
    }
    // bounce: D rows m=0,1 (valid batches) live in kg==0 lanes, regs j=0,1
    if (kg == 0){
      #pragma unroll
      for (int q=0;q<8;++q){
        int R = w*128 + q*16 + n15;
        bounce[R]        = (float)acc[q][0];
        bounce[1024 + R] = (float)acc[q][1];
      }
    }
    asm volatile("s_waitcnt lgkmcnt(0)\n\ts_barrier" ::: "memory");
    // h-compute: one h per thread
    float g4[4];
    #pragma unroll
    for (int gt=0;gt<4;++gt){
      float gs = bounce[bb*1024 + gt*256 + uu];
      float xd = dec8f(xgl[cur][bb*1024 + gt*256 + uu]);
      g4[gt] = gs*invQ + xd*0.0625f;
    }
    float cnew = fsig(g4[1])*cst + fsig(g4[0])*ftanh(g4[2]);
    cst = cnew;
    float h = fsig(g4[3])*ftanh(cnew);
    int hq = (int)rintf(h*127.f);
    Atile[nxt][bb*272+uu] = (unsigned char)(hq & 0xFF);
    hout[((size_t)(b0+bb)*SL + t)*256 + uu] = f2bf(h);
    if (i+1 < S) *(uint*)(&xgl[nxt][bb*1024 + uu*4]) = xv;
    asm volatile("s_waitcnt lgkmcnt(0)\n\ts_barrier" ::: "memory");
  }
  cbuf[(size_t)(dir*64 + b0 + bb)*256 + uu] = cst;
}

// K2: emission GEMM via MFMA: [65536 rows x 512] @ [512 x 48(35)] -> emis fp32.
__global__ __launch_bounds__(256) void emis_mfma(
    const unsigned short* __restrict__ hfu, const unsigned short* __restrict__ hbu,
    const float* __restrict__ clsw, const float* __restrict__ clsb,
    float* __restrict__ emis){
  __shared__ unsigned short wsm[48*520];
  __shared__ __align__(16) unsigned short alds[128*40];
  const int tid = threadIdx.x;
  const int lane = tid & 63;
  const int wid  = tid >> 6;
  for (int i=tid; i<6144; i+=256){
    int r = i >> 7, c4 = (i & 127)*4;
    uint2 pv;
    if (r < 35){
      float4 v = *(const float4*)(clsw + (size_t)r*512 + c4);
      pv.x = pk2(v.x, v.y); pv.y = pk2(v.z, v.w);
    } else { pv.x = 0u; pv.y = 0u; }
    *(uint2*)(wsm + r*520 + c4) = pv;
  }
  __syncthreads();
  floatx4 acc[2][3];
  #pragma unroll
  for (int mt=0;mt<2;++mt)
    #pragma unroll
    for (int nt=0;nt<3;++nt){ acc[mt][nt][0]=0;acc[mt][nt][1]=0;acc[mt][nt][2]=0;acc[mt][nt][3]=0; }

  const size_t row0 = (size_t)blockIdx.x*128;
  for (int ks=0; ks<16; ++ks){
    const unsigned short* hsrc = (ks<8) ? hfu : hbu;
    const int col = (ks&7)*32;
    __syncthreads();
    #pragma unroll
    for (int q=0;q<2;++q){
      int j = tid*2+q;
      int r = j>>2, c4 = j&3;
      uint4 v = *(const uint4*)(hsrc + (row0 + r)*256 + col + c4*8);
      *(uint4*)((char*)alds + r*80 + c4*16) = v;
    }
    __syncthreads();
    short8 bfv[3];
    #pragma unroll
    for (int nt=0;nt<3;++nt){
      int rr = nt*16 + (lane&15);
      bfv[nt] = *(const short8*)(wsm + rr*520 + ks*32 + (lane>>4)*8);
    }
    #pragma unroll
    for (int mt=0;mt<2;++mt){
      int r = (wid*2+mt)*16 + (lane&15);
      short8 af = *(const short8*)((char*)alds + r*80 + (lane>>4)*16);
      #pragma unroll
      for (int nt=0;nt<3;++nt)
        acc[mt][nt] = __builtin_amdgcn_mfma_f32_16x16x32_bf16(af, bfv[nt], acc[mt][nt], 0,0,0);
    }
  }
  #pragma unroll
  for (int mt=0;mt<2;++mt){
    #pragma unroll
    for (int nt=0;nt<3;++nt){
      int tag = nt*16 + (lane&15);
      if (tag < NT){
        float bv = clsb[tag];
        #pragma unroll
        for (int j=0;j<4;++j){
          int m = (wid*2+mt)*16 + (lane>>4)*4 + j;
          emis[(row0 + m)*NT + tag] = acc[mt][nt][j] + bv;
        }
      }
    }
  }
}

// K3: gold score + CRF forward. 1 wave per batch, wave-synchronous.
__global__ void crf_kernel(const float* __restrict__ emis, const float* __restrict__ trans,
                           const int* __restrict__ tags, float* __restrict__ diff){
  const int b = blockIdx.x, l = threadIdx.x;
  __shared__ float aLds[64];
  float gp = 0.f;
  for (int t=l; t<SL; t+=64){
    int tg = tags[b*SL+t];
    int pv = (t>0) ? tags[b*SL+t-1] : TSTART;
    gp += emis[((size_t)(b*SL)+t)*NT + tg] + trans[tg*NT+pv];
  }
  #pragma unroll
  for (int m=1;m<64;m<<=1) gp += __shfl_xor(gp, m);
  float Erow[NT];
  #pragma unroll
  for (int p=0;p<NT;++p) Erow[p] = (l<NT) ? __expf(trans[l*NT+p]) : 0.f;
  aLds[l] = (l==TSTART) ? 1.f : 0.f;
  float logZ = 0.f;
  const float* ep = emis + (size_t)b*SL*NT;
  float epre = (l<NT) ? ep[l] : 0.f;
  for (int t=0; t<SL; ++t){
    float ev = __expf(epre);
    int tn = (t+1 < SL) ? (t+1) : (SL-1);
    epre = (l<NT) ? ep[(size_t)tn*NT + l] : 0.f;
    float s0=0.f, s1=0.f, s2=0.f, s3=0.f;
    #pragma unroll
    for (int p=0;p<32;p+=4){
      s0 += Erow[p  ]*aLds[p  ];
      s1 += Erow[p+1]*aLds[p+1];
      s2 += Erow[p+2]*aLds[p+2];
      s3 += Erow[p+3]*aLds[p+3];
    }
    s0 += Erow[32]*aLds[32];
    s1 += Erow[33]*aLds[33];
    s2 += Erow[34]*aLds[34];
    float v = ((s0+s1)+(s2+s3)) * ev;
    float tot = v;
    #pragma unroll
    for (int m=1;m<64;m<<=1) tot += __shfl_xor(tot, m);
    logZ += __logf(tot);
    aLds[l] = v * __builtin_amdgcn_rcpf(tot);
  }
  if (l == 0) diff[b] = logZ - gp;
}

// K4: loss = mean(diff)
__global__ void final_kernel(const float* __restrict__ diff, float* __restrict__ out){
  int l = threadIdx.x;
  float v = diff[l];
  #pragma unroll
  for (int m=1;m<64;m<<=1) v += __shfl_xor(v, m);
  if (l == 0) out[0] = v * (1.f/64.f);
}

extern "C" void kernel_launch(void* const* d_in, const int* in_sizes, int n_in,
                              void* d_out, int out_size, void* d_ws, size_t ws_size,
                              hipStream_t stream){
  const int*   data = (const int*)d_in[0];
  const int*   tags = (const int*)d_in[2];
  const float* emb  = (const float*)d_in[3];
  const float* wihf = (const float*)d_in[4];
  const float* whhf = (const float*)d_in[5];
  const float* bihf = (const float*)d_in[6];
  const float* bhhf = (const float*)d_in[7];
  const float* wihb = (const float*)d_in[8];
  const float* whhb = (const float*)d_in[9];
  const float* bihb = (const float*)d_in[10];
  const float* bhhb = (const float*)d_in[11];
  const float* clsw = (const float*)d_in[12];
  const float* clsb = (const float*)d_in[13];
  const float* trans= (const float*)d_in[14];

  char* ws = (char*)d_ws;
  unsigned short* hf = (unsigned short*)(ws);              // 33,554,432 B
  unsigned short* hb = (unsigned short*)(ws + 33554432);   // 33,554,432 B
  float* cbuf = (float*)(ws + 67108864);                   //     65,536 B
  unsigned char* xgp = (unsigned char*)(ws + 67174400);    // 2*64*S*1024 B
  float* emis = (float*)(ws + 67174400);                   // overlays xg post-lstm

  // choose time-chunking from ws_size; worst case S=128 needs 83.95 MB.
  int S = 128;
  for (int cand = 1024; cand >= 128; cand >>= 1){
    size_t need = 67174400ull + (size_t)2*64*cand*1024 + 4096ull;
    if (need <= ws_size){ S = cand; break; }
  }
  const int NC = SL / S;
  const int logS = 31 - __builtin_clz((unsigned)S);
  float* diff = (float*)(ws + 67174400 + (size_t)2*64*S*1024);
  float* out  = (float*)d_out;

  for (int k=0; k<NC; ++k){
    int t0f = k*S, t0b = SL - (k+1)*S;
    xg_gemm<<<dim3(S*64/128, 8, 2), dim3(256), 0, stream>>>(
        data, emb, wihf, wihb, bihf, bhhf, bihb, bhhb, xgp, t0f, t0b, S, logS);
    lstm_rec<<<dim3(32, 2), dim3(512), 0, stream>>>(
        xgp, whhf, whhb, hf, hb, cbuf, t0f, t0b, S, (k==0) ? 1 : 0);
  }
  emis_mfma<<<dim3(512), dim3(256), 0, stream>>>(hf, hb, clsw, clsb, emis);
  crf_kernel<<<dim3(64), dim3(64), 0, stream>>>(emis, trans, tags, diff);
  final_kernel<<<dim3(1), dim3(64), 0, stream>>>(diff, out);
}